// Round 7
// baseline (769.447 us; speedup 1.0000x reference)
//
#include <hip/hip_runtime.h>
#include <stdint.h>

// ---------------------------------------------------------------------------
// Fused SAM-style attention block on MI355X (gfx950).  Round 7.
// Flash v7: 3 blocks/CU (LDS 48KB: K dbuf 2x4KB/wave + V single-buf 4KB/wave,
// WAR-guarded by lgkmcnt(0) before re-stage), barrier-free loop, counted
// vmcnt(6), softmax chain cut to add3+exp2 (SCALE*log2e folded into kg,
// log2e folded into rel producers).
// ---------------------------------------------------------------------------

typedef __attribute__((ext_vector_type(4))) float f32x4;
typedef __attribute__((ext_vector_type(16))) float f32x16;
typedef __attribute__((ext_vector_type(4))) float fvec4;
typedef __attribute__((ext_vector_type(8))) short s16x8;
typedef __attribute__((ext_vector_type(4))) short s16x4;
typedef __attribute__((ext_vector_type(4))) unsigned u32x4;

constexpr int NH  = 12;
constexpr int HD  = 64;
constexpr int DIM = 768;
constexpr int N   = 4096;
constexpr int QKV = 2304;
constexpr float LOG2E  = 1.4426950408889634f;
constexpr float SCALE2 = 0.125f * LOG2E;   // folded into kg at QKV epilogue

static __device__ __forceinline__ short f2bf(float f) {
  unsigned u = __builtin_bit_cast(unsigned, f);
  unsigned r = (u + 0x7FFFu + ((u >> 16) & 1u)) >> 16;  // RNE
  return (short)r;
}
static __device__ __forceinline__ float bf2f(short s) {
  unsigned u = ((unsigned)(unsigned short)s) << 16;
  return __builtin_bit_cast(float, u);
}
static __device__ __forceinline__ unsigned cvt_pk_bf16(float a, float b) {
  unsigned r;
  asm("v_cvt_pk_bf16_f32 %0, %1, %2" : "=v"(r) : "v"(a), "v"(b));
  return r;
}
static __device__ __forceinline__ float ex2(float x) {
  float r;
  asm("v_exp_f32 %0, %1" : "=v"(r) : "v"(x));
  return r;
}
static __device__ __forceinline__ void gload16(const void* g, void* l) {
  __builtin_amdgcn_global_load_lds(
      (const __attribute__((address_space(1))) void*)g,
      (__attribute__((address_space(3))) void*)l, 16, 0, 0);
}
static __device__ __forceinline__ void barrier_pre() {
  __builtin_amdgcn_s_barrier();
  __builtin_amdgcn_sched_barrier(0);
}
static __device__ __forceinline__ void barrier_post() {
  __builtin_amdgcn_sched_barrier(0);
  __builtin_amdgcn_s_barrier();
  __builtin_amdgcn_sched_barrier(0);
}

// ---------------------------------------------------------------------------
// K0: W_eff = w_qkv + lora_B @ lora_A  (bf16 out, [2304][768])
// ---------------------------------------------------------------------------
__global__ __launch_bounds__(256) void k_weff(const float* __restrict__ w_qkv,
                                              const float* __restrict__ lora_A,
                                              const float* __restrict__ lora_B,
                                              short* __restrict__ weff) {
  int e = blockIdx.x * 256 + threadIdx.x;
  if (e >= QKV * DIM) return;
  int r = e / DIM, c = e % DIM;
  float acc = w_qkv[e];
#pragma unroll
  for (int t = 0; t < 12; ++t) acc += lora_B[r * 12 + t] * lora_A[t * DIM + c];
  weff[e] = f2bf(acc);
}

// ---------------------------------------------------------------------------
// K0b: x fp32 -> bf16
// ---------------------------------------------------------------------------
__global__ __launch_bounds__(256) void k_x2bf(const float* __restrict__ x,
                                              short* __restrict__ xb) {
  int i = blockIdx.x * 256 + threadIdx.x;
  fvec4 v = *reinterpret_cast<const fvec4*>(x + (size_t)i * 4);
  s16x4 p;
  p[0] = f2bf(v[0]); p[1] = f2bf(v[1]); p[2] = f2bf(v[2]); p[3] = f2bf(v[3]);
  *reinterpret_cast<s16x4*>(xb + (size_t)i * 4) = p;
}

// ---------------------------------------------------------------------------
// K0c: w_proj -> split-bf16 B' [768][2304] = [Whi | Wlo | Whi]
// ---------------------------------------------------------------------------
__global__ __launch_bounds__(256) void k_wsplit(const float* __restrict__ w,
                                                short* __restrict__ ws) {
  int r = blockIdx.y;
  int kk = blockIdx.x * 256 + threadIdx.x;
  int blk = (kk >= 1536) ? 2 : (kk >= 768 ? 1 : 0);
  int c = kk - blk * 768;
  float wv = w[(size_t)r * 768 + c];
  short hi = f2bf(wv);
  ws[(size_t)r * 2304 + kk] = (blk == 1) ? f2bf(wv - bf2f(hi)) : hi;
}

// ---------------------------------------------------------------------------
// BMx128 MFMA GEMM, BK=64, double-buffered, counted vmcnt + raw barriers.
// MODE 0: qkv scatter (k scaled by SCALE2).  MODE 1: fp32 out + bias.
// ---------------------------------------------------------------------------
template <int KIT, int MODE, int BM>
__global__ __launch_bounds__(256, 2) void k_gemm(const short* __restrict__ A,
                                                 const short* __restrict__ B,
                                                 const float* __restrict__ bias,
                                                 short* __restrict__ qo,
                                                 short* __restrict__ ko,
                                                 short* __restrict__ vo,
                                                 float* __restrict__ outf) {
  constexpr int MFR = BM / 32;              // A m-frags per wave
  constexpr int BUFB = BM * 128 + 16384;    // bytes per buffer (A + B tiles)
  __shared__ __align__(16) char lds[2 * BUFB];
  const int tid = threadIdx.x;
  const int wave = tid >> 6, lane = tid & 63, lr = lane & 15, lg = lane >> 4;
  const int wr = wave >> 1, wc = wave & 1;
  const int i0 = blockIdx.x * BM, j0 = blockIdx.y * 128;
  const int LDA = KIT * 128;  // row bytes

  size_t offA[MFR], offB[4];
#pragma unroll
  for (int it = 0; it < MFR; ++it) {
    int c = it * 256 + tid;
    int row = c >> 3;
    offA[it] = (size_t)row * LDA + (((c & 7) << 4) ^ ((row & 7) << 4));
  }
#pragma unroll
  for (int it = 0; it < 4; ++it) {
    int c = it * 256 + tid;
    int row = c >> 3;
    offB[it] = (size_t)row * LDA + (((c & 7) << 4) ^ ((row & 7) << 4));
  }
  const char* Ab = (const char*)A + (size_t)i0 * LDA;
  const char* Bb = (const char*)B + (size_t)j0 * LDA;

  auto STAGE = [&](int kt, int b) {
    char* base = lds + b * BUFB;
    const size_t kadd = (size_t)kt * 128;
#pragma unroll
    for (int it = 0; it < MFR; ++it)
      gload16(Ab + kadd + offA[it], base + wave * 1024 + it * 4096);
#pragma unroll
    for (int it = 0; it < 4; ++it)
      gload16(Bb + kadd + offB[it], base + BM * 128 + wave * 1024 + it * 4096);
  };

  const int swz = (lr & 7) << 4;
  const int ab = (wr * (BM / 2) + lr) * 128 + ((lg * 16) ^ swz);
  const int bb = BM * 128 + (wc * 64 + lr) * 128 + ((lg * 16) ^ swz);

  f32x4 acc[MFR][4] = {};

  STAGE(0, 0);
  for (int kt = 0; kt < KIT; ++kt) {
    const int buf = kt & 1;
    if (kt + 1 < KIT) {
      STAGE(kt + 1, buf ^ 1);
      if constexpr (BM == 128)
        asm volatile("s_waitcnt vmcnt(8)" ::: "memory");
      else
        asm volatile("s_waitcnt vmcnt(6)" ::: "memory");
    } else {
      asm volatile("s_waitcnt vmcnt(0)" ::: "memory");
    }
    barrier_pre();
    const char* bufp = lds + buf * BUFB;
#pragma unroll
    for (int ks2 = 0; ks2 < 2; ++ks2) {
      s16x8 af[MFR], bf_[4];
#pragma unroll
      for (int m = 0; m < MFR; ++m)
        af[m] = *reinterpret_cast<const s16x8*>(bufp + ((ab + m * 2048) ^ (ks2 << 6)));
#pragma unroll
      for (int n = 0; n < 4; ++n)
        bf_[n] = *reinterpret_cast<const s16x8*>(bufp + ((bb + n * 2048) ^ (ks2 << 6)));
#pragma unroll
      for (int m = 0; m < MFR; ++m)
#pragma unroll
        for (int n = 0; n < 4; ++n)
          acc[m][n] = __builtin_amdgcn_mfma_f32_16x16x32_bf16(af[m], bf_[n], acc[m][n], 0, 0, 0);
    }
    barrier_post();
  }

  if constexpr (MODE == 0) {
    const int three = j0 / 768;
    const int head = ((j0 % 768) >> 6) + wc;
    const float osc = (three == 1) ? SCALE2 : 1.0f;  // fold SCALE*log2e into K
    short* dst = (three == 0) ? qo : ((three == 1) ? ko : vo);
#pragma unroll
    for (int n = 0; n < 4; ++n) {
      const int col = n * 16 + lr;
      const float bj = bias[j0 + wc * 64 + col];
#pragma unroll
      for (int m = 0; m < MFR; ++m)
#pragma unroll
        for (int r = 0; r < 4; ++r) {
          int i = i0 + wr * (BM / 2) + m * 16 + lg * 4 + r;
          dst[((size_t)head * N + i) * HD + col] = f2bf((acc[m][n][r] + bj) * osc);
        }
    }
  } else {
#pragma unroll
    for (int n = 0; n < 4; ++n) {
      const int j = j0 + wc * 64 + n * 16 + lr;
      const float bj = bias[j];
#pragma unroll
      for (int m = 0; m < MFR; ++m)
#pragma unroll
        for (int r = 0; r < 4; ++r) {
          int i = i0 + wr * (BM / 2) + m * 16 + lg * 4 + r;
          outf[(size_t)i * 768 + j] = acc[m][n][r] + bj;
        }
    }
  }
}

// ---------------------------------------------------------------------------
// K1b: vT[h][c][i] = v[h][i][c]
// ---------------------------------------------------------------------------
__global__ __launch_bounds__(256) void k_vT(const short* __restrict__ vg,
                                            short* __restrict__ vTg) {
  __shared__ short ts[64 * 72];
  const int tid = threadIdx.x;
  const int i0 = blockIdx.x * 64;
  const int h = blockIdx.y;
#pragma unroll
  for (int it = 0; it < 2; ++it) {
    int ch = tid + 256 * it;
    int row = ch >> 3, cc = (ch & 7) * 8;
    *reinterpret_cast<s16x8*>(&ts[row * 72 + cc]) =
        *reinterpret_cast<const s16x8*>(&vg[((size_t)h * N + i0 + row) * HD + cc]);
  }
  __syncthreads();
#pragma unroll
  for (int it = 0; it < 2; ++it) {
    int ch = tid + 256 * it;
    int c = ch >> 3, ii = (ch & 7) * 8;
    s16x8 o;
#pragma unroll
    for (int j = 0; j < 8; ++j) o[j] = ts[(ii + j) * 72 + c];
    *reinterpret_cast<s16x8*>(&vTg[((size_t)h * HD + c) * N + i0 + ii]) = o;
  }
}

// ---------------------------------------------------------------------------
// K2a: rel_h via MFMA, stored TRANSPOSED & pre-scaled by log2e:
// rhT[h][qh][kh][qw] = log2e * dot(q, tab[qh-kh+63])
// ---------------------------------------------------------------------------
__global__ __launch_bounds__(256) void k_relh(const short* __restrict__ qg,
                                              const float* __restrict__ tab,
                                              short* __restrict__ rhT) {
  __shared__ short Ts[64 * 72];
  const int tid = threadIdx.x;
  const int wave = tid >> 6, lane = tid & 63, lr = lane & 15, lg = lane >> 4;
  const int h = blockIdx.x >> 6, qh = blockIdx.x & 63;
#pragma unroll
  for (int it = 0; it < 4; ++it) {
    int e = tid + 256 * it;
    int row = e >> 4, c4 = (e & 15) * 4;  // row = kh
    fvec4 v = *reinterpret_cast<const fvec4*>(tab + (size_t)(qh + 63 - row) * 64 + c4);
    s16x4 p;
    p[0] = f2bf(v[0]); p[1] = f2bf(v[1]); p[2] = f2bf(v[2]); p[3] = f2bf(v[3]);
    *reinterpret_cast<s16x4*>(&Ts[row * 72 + c4]) = p;
  }
  __syncthreads();
  const size_t qrow = (size_t)h * N + qh * 64 + wave * 16 + lr;
  const s16x8 a0 = *reinterpret_cast<const s16x8*>(qg + qrow * 64 + lg * 8);
  const s16x8 a1 = *reinterpret_cast<const s16x8*>(qg + qrow * 64 + 32 + lg * 8);
  f32x4 acc[4] = {};
#pragma unroll
  for (int ks2 = 0; ks2 < 2; ++ks2)
#pragma unroll
    for (int n = 0; n < 4; ++n) {
      s16x8 b = *reinterpret_cast<const s16x8*>(&Ts[(n * 16 + lr) * 72 + ks2 * 32 + lg * 8]);
      acc[n] = __builtin_amdgcn_mfma_f32_16x16x32_bf16(ks2 ? a1 : a0, b, acc[n], 0, 0, 0);
    }
  const size_t ob = ((size_t)(h * 64 + qh)) * 4096;
#pragma unroll
  for (int n = 0; n < 4; ++n) {
    s16x4 o;
#pragma unroll
    for (int r = 0; r < 4; ++r) o[r] = f2bf(acc[n][r] * LOG2E);
    *reinterpret_cast<s16x4*>(&rhT[ob + (size_t)(n * 16 + lr) * 64 + wave * 16 + lg * 4]) = o;
  }
}

// ---------------------------------------------------------------------------
// K2b: rel_w via U-GEMM + scatter, pre-scaled by log2e.
// ---------------------------------------------------------------------------
__global__ __launch_bounds__(256) void k_relw(const short* __restrict__ qg,
                                              const float* __restrict__ tab,
                                              short* __restrict__ rwg) {
  __shared__ short Ts[128 * 72];
  const int tid = threadIdx.x;
  const int wave = tid >> 6, lane = tid & 63, lr = lane & 15, lg = lane >> 4;
  const int h = blockIdx.x >> 6, qh = blockIdx.x & 63;
#pragma unroll
  for (int it = 0; it < 8; ++it) {
    int e = tid + 256 * it;
    int row = e >> 4, c4 = (e & 15) * 4;  // row = d
    s16x4 p = {0, 0, 0, 0};
    if (row < 127) {
      fvec4 v = *reinterpret_cast<const fvec4*>(tab + (size_t)row * 64 + c4);
      p[0] = f2bf(v[0]); p[1] = f2bf(v[1]); p[2] = f2bf(v[2]); p[3] = f2bf(v[3]);
    }
    *reinterpret_cast<s16x4*>(&Ts[row * 72 + c4]) = p;
  }
  __syncthreads();
  const size_t qrow = (size_t)h * N + qh * 64 + wave * 16 + lr;
  const s16x8 a0 = *reinterpret_cast<const s16x8*>(qg + qrow * 64 + lg * 8);
  const s16x8 a1 = *reinterpret_cast<const s16x8*>(qg + qrow * 64 + 32 + lg * 8);
  f32x4 acc[8] = {};
#pragma unroll
  for (int ks2 = 0; ks2 < 2; ++ks2)
#pragma unroll
    for (int n = 0; n < 8; ++n) {
      s16x8 b = *reinterpret_cast<const s16x8*>(&Ts[(n * 16 + lr) * 72 + ks2 * 32 + lg * 8]);
      acc[n] = __builtin_amdgcn_mfma_f32_16x16x32_bf16(ks2 ? a1 : a0, b, acc[n], 0, 0, 0);
    }
  const size_t ob = ((size_t)h * N + qh * 64) * 64;
#pragma unroll
  for (int n = 0; n < 8; ++n) {
    int d = n * 16 + lr;
#pragma unroll
    for (int r = 0; r < 4; ++r) {
      int qw = wave * 16 + lg * 4 + r;
      int kw = qw + 63 - d;
      if ((unsigned)kw < 64u) rwg[ob + (size_t)qw * 64 + kw] = f2bf(acc[n][r] * LOG2E);
    }
  }
}

// ---------------------------------------------------------------------------
// K3: flash attention v7.  Barrier-free, 48KB LDS (3 blocks/CU).
// Per-wave region (12KB): K dbuf @0/@4096 (32 rows x 128B each),
// V single-buf @8192 (32 rows x 128B; row r = {V^T[c=r][32 keys], V^T[c=r+32]}).
// V WAR guard: ds_read V -> lgkmcnt(0) -> STAGE_V(next).  Counted vmcnt(6).
// Softmax: p = exp2(sa + rh + rw)  (scales folded upstream).
// ---------------------------------------------------------------------------
#define QG_BLOCK(QB0, QB1, QB2, QB3, RW, RH2, ACC0, ACC1, LA, LB)              \
  do {                                                                         \
    f32x16 sa = {};                                                            \
    __builtin_amdgcn_s_setprio(1);                                             \
    sa = __builtin_amdgcn_mfma_f32_32x32x16_bf16(kf0, QB0, sa, 0, 0, 0);       \
    sa = __builtin_amdgcn_mfma_f32_32x32x16_bf16(kf1, QB1, sa, 0, 0, 0);       \
    sa = __builtin_amdgcn_mfma_f32_32x32x16_bf16(kf2, QB2, sa, 0, 0, 0);       \
    sa = __builtin_amdgcn_mfma_f32_32x32x16_bf16(kf3, QB3, sa, 0, 0, 0);       \
    __builtin_amdgcn_s_setprio(0);                                             \
    float p[16];                                                               \
    _Pragma("unroll")                                                          \
    for (int reg = 0; reg < 16; ++reg)                                         \
      p[reg] = ex2(sa[reg] + RH2 + RW[reg]);                                   \
    float t0 = (p[0] + p[1]) + (p[2] + p[3]);                                  \
    float t1 = (p[4] + p[5]) + (p[6] + p[7]);                                  \
    float t2 = (p[8] + p[9]) + (p[10] + p[11]);                                \
    float t3 = (p[12] + p[13]) + (p[14] + p[15]);                              \
    LA += t0 + t1;                                                             \
    LB += t2 + t3;                                                             \
    unsigned w00 = cvt_pk_bf16(p[0], p[1]),   w01 = cvt_pk_bf16(p[2], p[3]);   \
    unsigned w10 = cvt_pk_bf16(p[4], p[5]),   w11 = cvt_pk_bf16(p[6], p[7]);   \
    unsigned w20 = cvt_pk_bf16(p[8], p[9]),   w21 = cvt_pk_bf16(p[10], p[11]); \
    unsigned w30 = cvt_pk_bf16(p[12], p[13]), w31 = cvt_pk_bf16(p[14], p[15]); \
    asm("v_permlane32_swap_b32 %0, %1" : "+v"(w00), "+v"(w10));                \
    asm("v_permlane32_swap_b32 %0, %1" : "+v"(w01), "+v"(w11));                \
    asm("v_permlane32_swap_b32 %0, %1" : "+v"(w20), "+v"(w30));                \
    asm("v_permlane32_swap_b32 %0, %1" : "+v"(w21), "+v"(w31));                \
    u32x4 u0 = {w00, w01, w10, w11};                                           \
    u32x4 u1 = {w20, w21, w30, w31};                                           \
    s16x8 pa0 = __builtin_bit_cast(s16x8, u0);                                 \
    s16x8 pa1 = __builtin_bit_cast(s16x8, u1);                                 \
    __builtin_amdgcn_s_setprio(1);                                             \
    ACC0 = __builtin_amdgcn_mfma_f32_32x32x16_bf16(pa0, vf0, ACC0, 0, 0, 0);   \
    ACC0 = __builtin_amdgcn_mfma_f32_32x32x16_bf16(pa1, vf2, ACC0, 0, 0, 0);   \
    ACC1 = __builtin_amdgcn_mfma_f32_32x32x16_bf16(pa0, vf1, ACC1, 0, 0, 0);   \
    ACC1 = __builtin_amdgcn_mfma_f32_32x32x16_bf16(pa1, vf3, ACC1, 0, 0, 0);   \
    __builtin_amdgcn_s_setprio(0);                                             \
  } while (0)

// read K(i) from kbuf, V(i) from single V buf; then WAR-guard + stage V(NEXT)
#define FLASH_BODY(KBUFOFF, STAGE_V_NEXT, RHU0, RHU1)                          \
  do {                                                                         \
    const char* kb = wb + (KBUFOFF);                                           \
    s16x8 kf0 = *reinterpret_cast<const s16x8*>(kb + kco0);                    \
    s16x8 kf1 = *reinterpret_cast<const s16x8*>(kb + kco1);                    \
    s16x8 kf2 = *reinterpret_cast<const s16x8*>(kb + kco2);                    \
    s16x8 kf3 = *reinterpret_cast<const s16x8*>(kb + kco3);                    \
    s16x8 vf0 = *reinterpret_cast<const s16x8*>(wb + vco0);                    \
    s16x8 vf1 = *reinterpret_cast<const s16x8*>(wb + vco1);                    \
    s16x8 vf2 = *reinterpret_cast<const s16x8*>(wb + vco2);                    \
    s16x8 vf3 = *reinterpret_cast<const s16x8*>(wb + vco3);                    \
    asm volatile("s_waitcnt lgkmcnt(0)" ::: "memory");                         \
    __builtin_amdgcn_sched_barrier(0);                                         \
    STAGE_V_NEXT;                                                              \
    const float rh20 = bf2f((short)(RHU0));                                    \
    const float rh21 = bf2f((short)(RHU1));                                    \
    QG_BLOCK(qb00, qb01, qb02, qb03, rw0, rh20, acc00, acc01, la0, lb0);       \
    QG_BLOCK(qb10, qb11, qb12, qb13, rw1, rh21, acc10, acc11, la1, lb1);       \
  } while (0)

__global__ __launch_bounds__(256, 3) void k_flash(const short* __restrict__ qg,
                                                  const short* __restrict__ kg,
                                                  const short* __restrict__ vTg,
                                                  const short* __restrict__ rhTg,
                                                  const short* __restrict__ rwg,
                                                  short* __restrict__ aprime) {
  __shared__ __align__(16) char lds[49152];
  const int tid = threadIdx.x;
  const int wave = tid >> 6, lane = tid & 63;
  const int ql = lane & 31, hi = lane >> 5;
  const int kt2 = wave & 1, kh2 = wave >> 1;
  const int bid = blockIdx.x;
  const int id = (bid & 7) * 96 + (bid >> 3);  // bijective XCD swizzle (768%8==0)
  const int h = id >> 6, qt = id & 63;
  const int i0 = qt * 64;

  // Q fragments in registers
  const short* q0p = qg + ((size_t)h * N + i0 + ql) * 64 + hi * 8;
  const short* q1p = q0p + 32 * 64;
  const s16x8 qb00 = *reinterpret_cast<const s16x8*>(q0p);
  const s16x8 qb01 = *reinterpret_cast<const s16x8*>(q0p + 16);
  const s16x8 qb02 = *reinterpret_cast<const s16x8*>(q0p + 32);
  const s16x8 qb03 = *reinterpret_cast<const s16x8*>(q0p + 48);
  const s16x8 qb10 = *reinterpret_cast<const s16x8*>(q1p);
  const s16x8 qb11 = *reinterpret_cast<const s16x8*>(q1p + 16);
  const s16x8 qb12 = *reinterpret_cast<const s16x8*>(q1p + 32);
  const s16x8 qb13 = *reinterpret_cast<const s16x8*>(q1p + 48);

  // rel_w preload (already log2e-scaled by producer)
  f32x16 rw0, rw1;
  {
    const short* rwp0 = rwg + ((size_t)h * N + i0 + ql) * 64 + kh2 * 32 + hi * 4;
    const short* rwp1 = rwp0 + 32 * 64;
#pragma unroll
    for (int reg = 0; reg < 16; ++reg) {
      int o = (reg & 3) + 8 * (reg >> 2);
      rw0[reg] = bf2f(rwp0[o]);
      rw1[reg] = bf2f(rwp1[o]);
    }
  }
  const short* rhp = rhTg + ((size_t)(h * 64 + qt)) * 4096;

  // own-slice staging offsets (inverse-swizzled)
  const int kbrow = kt2 * 64 + kh2 * 32;   // wave's first key
  int koff[4], voff[4];
#pragma unroll
  for (int it = 0; it < 4; ++it) {
    int c = it * 64 + lane;
    int row = c >> 3, pos = c & 7, s = pos ^ (row & 7);
    koff[it] = (kbrow + row) * 128 + s * 16;
  }
#pragma unroll
  for (int it = 0; it < 4; ++it) {
    int c = it * 64 + lane;
    int r = c >> 3, pos = c & 7, s = pos ^ (r & 7);
    voff[it] = (r + ((s >> 2) << 5)) * 8192 + (kbrow + ((s & 3) << 3)) * 2;
  }
  const char* kgb = (const char*)kg + (size_t)h * N * 128;
  const char* vgb = (const char*)vTg + (size_t)h * 64 * 8192;
  char* wb = lds + wave * 12288;   // K0 @0, K1 @4096, V @8192

  auto STAGE_K = [&](int i, int buf) {
    const char* kp = kgb + (size_t)i * 16384;
    char* lp = wb + buf * 4096;
#pragma unroll
    for (int it = 0; it < 4; ++it) gload16(kp + koff[it], lp + it * 1024);
  };
  auto STAGE_V = [&](int i) {
    const char* vp = vgb + (size_t)i * 256;
    char* lp = wb + 8192;
#pragma unroll
    for (int it = 0; it < 4; ++it) gload16(vp + voff[it], lp + it * 1024);
  };

  // fragment read offsets (within wave region)
  const int swzq = (ql & 7) << 4;
  const int kco0 = ql * 128 + ((0 * 32 + hi * 16) ^ swzq);
  const int kco1 = ql * 128 + ((1 * 32 + hi * 16) ^ swzq);
  const int kco2 = ql * 128 + ((2 * 32 + hi * 16) ^ swzq);
  const int kco3 = ql * 128 + ((3 * 32 + hi * 16) ^ swzq);
  const int vco0 = 8192 + ql * 128 + ((0 * 64 + 0 * 32 + hi * 16) ^ swzq);  // ks0 ct0
  const int vco1 = 8192 + ql * 128 + ((1 * 64 + 0 * 32 + hi * 16) ^ swzq);  // ks0 ct1
  const int vco2 = 8192 + ql * 128 + ((0 * 64 + 1 * 32 + hi * 16) ^ swzq);  // ks1 ct0
  const int vco3 = 8192 + ql * 128 + ((1 * 64 + 1 * 32 + hi * 16) ^ swzq);  // ks1 ct1

  f32x16 acc00 = {}, acc01 = {}, acc10 = {}, acc11 = {};
  float la0 = 0.f, lb0 = 0.f, la1 = 0.f, lb1 = 0.f;

  // prologue: K(0) + rh(0) + V(0) -> 10 vmem in flight
  STAGE_K(0, 0);
  unsigned short rA0 = (unsigned short)rhp[(size_t)kt2 * 64 + ql];
  unsigned short rA1 = (unsigned short)rhp[(size_t)kt2 * 64 + 32 + ql];
  STAGE_V(0);
  unsigned short rB0 = 0, rB1 = 0;

  for (int ii = 0; ii < 16; ++ii) {
    const int i = 2 * ii;
    // even iter: K from buf0; prefetch K(i+1)->buf1, rh(i+1); V(i+1) staged
    // inside FLASH_BODY after the V reads retire.
    STAGE_K(i + 1, 1);
    rB0 = (unsigned short)rhp[(size_t)((i + 1) * 2 + kt2) * 64 + ql];
    rB1 = (unsigned short)rhp[(size_t)((i + 1) * 2 + kt2) * 64 + 32 + ql];
    asm volatile("s_waitcnt vmcnt(6)" ::: "memory");  // K(i), rh(i), V(i) landed
    __builtin_amdgcn_sched_barrier(0);
    FLASH_BODY(0, STAGE_V(i + 1), rA0, rA1);
    // odd iter
    if (i + 2 < 32) {
      STAGE_K(i + 2, 0);
      rA0 = (unsigned short)rhp[(size_t)((i + 2) * 2 + kt2) * 64 + ql];
      rA1 = (unsigned short)rhp[(size_t)((i + 2) * 2 + kt2) * 64 + 32 + ql];
      asm volatile("s_waitcnt vmcnt(6)" ::: "memory");
      __builtin_amdgcn_sched_barrier(0);
      FLASH_BODY(4096, STAGE_V(i + 2), rB0, rB1);
    } else {
      asm volatile("s_waitcnt vmcnt(0)" ::: "memory");
      __builtin_amdgcn_sched_barrier(0);
      FLASH_BODY(4096, (void)0, rB0, rB1);
    }
  }

  // ---- epilogue: cross-wave reduction of l and O ----
  __syncthreads();   // waves skewed; sync before LDS reuse
  float l0 = la0 + lb0, l1 = la1 + lb1;
  l0 += __shfl_xor(l0, 32);
  l1 += __shfl_xor(l1, 32);
  float* LS = (float*)lds;               // [4 waves][64 q] @0 (1KB)
  if (lane < 32) {
    LS[wave * 64 + ql] = l0;
    LS[wave * 64 + 32 + ql] = l1;
  }
  __syncthreads();
  const int eq = tid >> 2;               // q row 0..63
  const int cq = (tid & 3) * 8;          // col chunk within 32-col half
  float inv = 1.0f / (LS[eq] + LS[64 + eq] + LS[128 + eq] + LS[192 + eq]);
  float* OF = (float*)(lds + 4096);      // [4 waves][64 q][32 c] per pass (32KB)
  const size_t obase = (size_t)(i0 + eq) * 2304 + h * 64;

#pragma unroll
  for (int ct = 0; ct < 2; ++ct) {
    __syncthreads();
    const f32x16& a0 = ct ? acc01 : acc00;   // q-group 0
    const f32x16& a1 = ct ? acc11 : acc10;   // q-group 1
#pragma unroll
    for (int reg = 0; reg < 16; ++reg) {
      int qr = (reg & 3) + 8 * (reg >> 2) + 4 * hi;
      int sw = (qr & 3) << 3;
      OF[wave * 2048 + qr * 32 + (ql ^ sw)] = a0[reg];
      OF[wave * 2048 + (32 + qr) * 32 + (ql ^ sw)] = a1[reg];
    }
    __syncthreads();
    float osum[8];
#pragma unroll
    for (int j = 0; j < 8; ++j) {
      int cs = (cq + j) ^ ((eq & 3) << 3);
      osum[j] = OF[eq * 32 + cs] + OF[2048 + eq * 32 + cs] +
                OF[4096 + eq * 32 + cs] + OF[6144 + eq * 32 + cs];
    }
    s16x8 h8, l8;
#pragma unroll
    for (int j = 0; j < 8; ++j) {
      float o = osum[j] * inv;
      short oh = f2bf(o);
      h8[j] = oh;
      l8[j] = f2bf(o - bf2f(oh));
    }
    size_t ob2 = obase + ct * 32 + cq;
    *reinterpret_cast<s16x8*>(&aprime[ob2]) = h8;
    *reinterpret_cast<s16x8*>(&aprime[ob2 + 768]) = h8;
    *reinterpret_cast<s16x8*>(&aprime[ob2 + 1536]) = l8;
  }
}

// ---------------------------------------------------------------------------
extern "C" void kernel_launch(void* const* d_in, const int* in_sizes, int n_in,
                              void* d_out, int out_size, void* d_ws, size_t ws_size,
                              hipStream_t stream) {
  const float* x      = (const float*)d_in[0];
  const float* w_qkv  = (const float*)d_in[1];
  const float* b_qkv  = (const float*)d_in[2];
  const float* lora_A = (const float*)d_in[3];
  const float* lora_B = (const float*)d_in[4];
  const float* w_proj = (const float*)d_in[5];
  const float* b_proj = (const float*)d_in[6];
  const float* rel_h  = (const float*)d_in[7];
  const float* rel_w  = (const float*)d_in[8];
  float* out = (float*)d_out;

  char* ws = (char*)d_ws;
  short* weff   = (short*)(ws + 0);           // dead before flash
  short* xb     = (short*)(ws + 3538944);     // dead before flash
  short* vg     = (short*)(ws + 9830400);     // dead before flash
  short* aprime = (short*)(ws + 0);           // overlays the above
  short* qg     = (short*)(ws + 18874368);
  short* kg     = (short*)(ws + 25165824);
  short* vTg    = (short*)(ws + 31457280);
  short* rhT    = (short*)(ws + 37748736);
  short* rwg    = (short*)(ws + 44040192);
  short* wsp    = (short*)(ws + 50331648);    // -> total 53,870,592
  (void)ws_size; (void)in_sizes; (void)n_in; (void)out_size;

  k_weff<<<dim3((QKV * DIM + 255) / 256), dim3(256), 0, stream>>>(w_qkv, lora_A, lora_B, weff);
  k_x2bf<<<dim3(3072), dim3(256), 0, stream>>>(x, xb);
  k_wsplit<<<dim3(9, 768), dim3(256), 0, stream>>>(w_proj, wsp);
  k_gemm<12, 0, 128><<<dim3(32, 18), dim3(256), 0, stream>>>(xb, weff, b_qkv, qg, kg, vg, nullptr);
  k_vT<<<dim3(64, NH), dim3(256), 0, stream>>>(vg, vTg);
  k_relh<<<dim3(NH * 64), dim3(256), 0, stream>>>(qg, rel_h, rhT);
  k_relw<<<dim3(NH * 64), dim3(256), 0, stream>>>(qg, rel_w, rwg);
  k_flash<<<dim3(NH * 64), dim3(256), 0, stream>>>(qg, kg, vTg, rhT, rwg, aprime);
  k_gemm<36, 1, 64><<<dim3(64, 6), dim3(256), 0, stream>>>(aprime, wsp, b_proj, nullptr, nullptr, nullptr, out);
}

// Round 8
// 395.016 us; speedup vs baseline: 1.9479x; 1.9479x over previous
//
#include <hip/hip_runtime.h>
#include <stdint.h>

// ---------------------------------------------------------------------------
// Fused SAM-style attention block on MI355X (gfx950).  Round 8.
// = Round 7 (48KB LDS, V single-buffer + lgkmcnt WAR guard, folded scales,
// barrier-free counted-vmcnt loop) but with __launch_bounds__(256,2) on
// k_flash: the (256,3) cap spilled the f32x16 accumulators to scratch
// (VGPR 128->84, 2.8GB scratch traffic, 8x slowdown).  3 blocks/CU now come
// from the 48KB LDS limit alone; 128 VGPR allows 4 waves/SIMD.
// ---------------------------------------------------------------------------

typedef __attribute__((ext_vector_type(4))) float f32x4;
typedef __attribute__((ext_vector_type(16))) float f32x16;
typedef __attribute__((ext_vector_type(4))) float fvec4;
typedef __attribute__((ext_vector_type(8))) short s16x8;
typedef __attribute__((ext_vector_type(4))) short s16x4;
typedef __attribute__((ext_vector_type(4))) unsigned u32x4;

constexpr int NH  = 12;
constexpr int HD  = 64;
constexpr int DIM = 768;
constexpr int N   = 4096;
constexpr int QKV = 2304;
constexpr float LOG2E  = 1.4426950408889634f;
constexpr float SCALE2 = 0.125f * LOG2E;   // folded into kg at QKV epilogue

static __device__ __forceinline__ short f2bf(float f) {
  unsigned u = __builtin_bit_cast(unsigned, f);
  unsigned r = (u + 0x7FFFu + ((u >> 16) & 1u)) >> 16;  // RNE
  return (short)r;
}
static __device__ __forceinline__ float bf2f(short s) {
  unsigned u = ((unsigned)(unsigned short)s) << 16;
  return __builtin_bit_cast(float, u);
}
static __device__ __forceinline__ unsigned cvt_pk_bf16(float a, float b) {
  unsigned r;
  asm("v_cvt_pk_bf16_f32 %0, %1, %2" : "=v"(r) : "v"(a), "v"(b));
  return r;
}
static __device__ __forceinline__ float ex2(float x) {
  float r;
  asm("v_exp_f32 %0, %1" : "=v"(r) : "v"(x));
  return r;
}
static __device__ __forceinline__ void gload16(const void* g, void* l) {
  __builtin_amdgcn_global_load_lds(
      (const __attribute__((address_space(1))) void*)g,
      (__attribute__((address_space(3))) void*)l, 16, 0, 0);
}
static __device__ __forceinline__ void barrier_pre() {
  __builtin_amdgcn_s_barrier();
  __builtin_amdgcn_sched_barrier(0);
}
static __device__ __forceinline__ void barrier_post() {
  __builtin_amdgcn_sched_barrier(0);
  __builtin_amdgcn_s_barrier();
  __builtin_amdgcn_sched_barrier(0);
}

// ---------------------------------------------------------------------------
// K0: W_eff = w_qkv + lora_B @ lora_A  (bf16 out, [2304][768])
// ---------------------------------------------------------------------------
__global__ __launch_bounds__(256) void k_weff(const float* __restrict__ w_qkv,
                                              const float* __restrict__ lora_A,
                                              const float* __restrict__ lora_B,
                                              short* __restrict__ weff) {
  int e = blockIdx.x * 256 + threadIdx.x;
  if (e >= QKV * DIM) return;
  int r = e / DIM, c = e % DIM;
  float acc = w_qkv[e];
#pragma unroll
  for (int t = 0; t < 12; ++t) acc += lora_B[r * 12 + t] * lora_A[t * DIM + c];
  weff[e] = f2bf(acc);
}

// ---------------------------------------------------------------------------
// K0b: x fp32 -> bf16
// ---------------------------------------------------------------------------
__global__ __launch_bounds__(256) void k_x2bf(const float* __restrict__ x,
                                              short* __restrict__ xb) {
  int i = blockIdx.x * 256 + threadIdx.x;
  fvec4 v = *reinterpret_cast<const fvec4*>(x + (size_t)i * 4);
  s16x4 p;
  p[0] = f2bf(v[0]); p[1] = f2bf(v[1]); p[2] = f2bf(v[2]); p[3] = f2bf(v[3]);
  *reinterpret_cast<s16x4*>(xb + (size_t)i * 4) = p;
}

// ---------------------------------------------------------------------------
// K0c: w_proj -> split-bf16 B' [768][2304] = [Whi | Wlo | Whi]
// ---------------------------------------------------------------------------
__global__ __launch_bounds__(256) void k_wsplit(const float* __restrict__ w,
                                                short* __restrict__ ws) {
  int r = blockIdx.y;
  int kk = blockIdx.x * 256 + threadIdx.x;
  int blk = (kk >= 1536) ? 2 : (kk >= 768 ? 1 : 0);
  int c = kk - blk * 768;
  float wv = w[(size_t)r * 768 + c];
  short hi = f2bf(wv);
  ws[(size_t)r * 2304 + kk] = (blk == 1) ? f2bf(wv - bf2f(hi)) : hi;
}

// ---------------------------------------------------------------------------
// BMx128 MFMA GEMM, BK=64, double-buffered, counted vmcnt + raw barriers.
// MODE 0: qkv scatter (k scaled by SCALE2).  MODE 1: fp32 out + bias.
// ---------------------------------------------------------------------------
template <int KIT, int MODE, int BM>
__global__ __launch_bounds__(256, 2) void k_gemm(const short* __restrict__ A,
                                                 const short* __restrict__ B,
                                                 const float* __restrict__ bias,
                                                 short* __restrict__ qo,
                                                 short* __restrict__ ko,
                                                 short* __restrict__ vo,
                                                 float* __restrict__ outf) {
  constexpr int MFR = BM / 32;              // A m-frags per wave
  constexpr int BUFB = BM * 128 + 16384;    // bytes per buffer (A + B tiles)
  __shared__ __align__(16) char lds[2 * BUFB];
  const int tid = threadIdx.x;
  const int wave = tid >> 6, lane = tid & 63, lr = lane & 15, lg = lane >> 4;
  const int wr = wave >> 1, wc = wave & 1;
  const int i0 = blockIdx.x * BM, j0 = blockIdx.y * 128;
  const int LDA = KIT * 128;  // row bytes

  size_t offA[MFR], offB[4];
#pragma unroll
  for (int it = 0; it < MFR; ++it) {
    int c = it * 256 + tid;
    int row = c >> 3;
    offA[it] = (size_t)row * LDA + (((c & 7) << 4) ^ ((row & 7) << 4));
  }
#pragma unroll
  for (int it = 0; it < 4; ++it) {
    int c = it * 256 + tid;
    int row = c >> 3;
    offB[it] = (size_t)row * LDA + (((c & 7) << 4) ^ ((row & 7) << 4));
  }
  const char* Ab = (const char*)A + (size_t)i0 * LDA;
  const char* Bb = (const char*)B + (size_t)j0 * LDA;

  auto STAGE = [&](int kt, int b) {
    char* base = lds + b * BUFB;
    const size_t kadd = (size_t)kt * 128;
#pragma unroll
    for (int it = 0; it < MFR; ++it)
      gload16(Ab + kadd + offA[it], base + wave * 1024 + it * 4096);
#pragma unroll
    for (int it = 0; it < 4; ++it)
      gload16(Bb + kadd + offB[it], base + BM * 128 + wave * 1024 + it * 4096);
  };

  const int swz = (lr & 7) << 4;
  const int ab = (wr * (BM / 2) + lr) * 128 + ((lg * 16) ^ swz);
  const int bb = BM * 128 + (wc * 64 + lr) * 128 + ((lg * 16) ^ swz);

  f32x4 acc[MFR][4] = {};

  STAGE(0, 0);
  for (int kt = 0; kt < KIT; ++kt) {
    const int buf = kt & 1;
    if (kt + 1 < KIT) {
      STAGE(kt + 1, buf ^ 1);
      if constexpr (BM == 128)
        asm volatile("s_waitcnt vmcnt(8)" ::: "memory");
      else
        asm volatile("s_waitcnt vmcnt(6)" ::: "memory");
    } else {
      asm volatile("s_waitcnt vmcnt(0)" ::: "memory");
    }
    barrier_pre();
    const char* bufp = lds + buf * BUFB;
#pragma unroll
    for (int ks2 = 0; ks2 < 2; ++ks2) {
      s16x8 af[MFR], bf_[4];
#pragma unroll
      for (int m = 0; m < MFR; ++m)
        af[m] = *reinterpret_cast<const s16x8*>(bufp + ((ab + m * 2048) ^ (ks2 << 6)));
#pragma unroll
      for (int n = 0; n < 4; ++n)
        bf_[n] = *reinterpret_cast<const s16x8*>(bufp + ((bb + n * 2048) ^ (ks2 << 6)));
#pragma unroll
      for (int m = 0; m < MFR; ++m)
#pragma unroll
        for (int n = 0; n < 4; ++n)
          acc[m][n] = __builtin_amdgcn_mfma_f32_16x16x32_bf16(af[m], bf_[n], acc[m][n], 0, 0, 0);
    }
    barrier_post();
  }

  if constexpr (MODE == 0) {
    const int three = j0 / 768;
    const int head = ((j0 % 768) >> 6) + wc;
    const float osc = (three == 1) ? SCALE2 : 1.0f;  // fold SCALE*log2e into K
    short* dst = (three == 0) ? qo : ((three == 1) ? ko : vo);
#pragma unroll
    for (int n = 0; n < 4; ++n) {
      const int col = n * 16 + lr;
      const float bj = bias[j0 + wc * 64 + col];
#pragma unroll
      for (int m = 0; m < MFR; ++m)
#pragma unroll
        for (int r = 0; r < 4; ++r) {
          int i = i0 + wr * (BM / 2) + m * 16 + lg * 4 + r;
          dst[((size_t)head * N + i) * HD + col] = f2bf((acc[m][n][r] + bj) * osc);
        }
    }
  } else {
#pragma unroll
    for (int n = 0; n < 4; ++n) {
      const int j = j0 + wc * 64 + n * 16 + lr;
      const float bj = bias[j];
#pragma unroll
      for (int m = 0; m < MFR; ++m)
#pragma unroll
        for (int r = 0; r < 4; ++r) {
          int i = i0 + wr * (BM / 2) + m * 16 + lg * 4 + r;
          outf[(size_t)i * 768 + j] = acc[m][n][r] + bj;
        }
    }
  }
}

// ---------------------------------------------------------------------------
// K1b: vT[h][c][i] = v[h][i][c]
// ---------------------------------------------------------------------------
__global__ __launch_bounds__(256) void k_vT(const short* __restrict__ vg,
                                            short* __restrict__ vTg) {
  __shared__ short ts[64 * 72];
  const int tid = threadIdx.x;
  const int i0 = blockIdx.x * 64;
  const int h = blockIdx.y;
#pragma unroll
  for (int it = 0; it < 2; ++it) {
    int ch = tid + 256 * it;
    int row = ch >> 3, cc = (ch & 7) * 8;
    *reinterpret_cast<s16x8*>(&ts[row * 72 + cc]) =
        *reinterpret_cast<const s16x8*>(&vg[((size_t)h * N + i0 + row) * HD + cc]);
  }
  __syncthreads();
#pragma unroll
  for (int it = 0; it < 2; ++it) {
    int ch = tid + 256 * it;
    int c = ch >> 3, ii = (ch & 7) * 8;
    s16x8 o;
#pragma unroll
    for (int j = 0; j < 8; ++j) o[j] = ts[(ii + j) * 72 + c];
    *reinterpret_cast<s16x8*>(&vTg[((size_t)h * HD + c) * N + i0 + ii]) = o;
  }
}

// ---------------------------------------------------------------------------
// K2a: rel_h via MFMA, stored TRANSPOSED & pre-scaled by log2e:
// rhT[h][qh][kh][qw] = log2e * dot(q, tab[qh-kh+63])
// ---------------------------------------------------------------------------
__global__ __launch_bounds__(256) void k_relh(const short* __restrict__ qg,
                                              const float* __restrict__ tab,
                                              short* __restrict__ rhT) {
  __shared__ short Ts[64 * 72];
  const int tid = threadIdx.x;
  const int wave = tid >> 6, lane = tid & 63, lr = lane & 15, lg = lane >> 4;
  const int h = blockIdx.x >> 6, qh = blockIdx.x & 63;
#pragma unroll
  for (int it = 0; it < 4; ++it) {
    int e = tid + 256 * it;
    int row = e >> 4, c4 = (e & 15) * 4;  // row = kh
    fvec4 v = *reinterpret_cast<const fvec4*>(tab + (size_t)(qh + 63 - row) * 64 + c4);
    s16x4 p;
    p[0] = f2bf(v[0]); p[1] = f2bf(v[1]); p[2] = f2bf(v[2]); p[3] = f2bf(v[3]);
    *reinterpret_cast<s16x4*>(&Ts[row * 72 + c4]) = p;
  }
  __syncthreads();
  const size_t qrow = (size_t)h * N + qh * 64 + wave * 16 + lr;
  const s16x8 a0 = *reinterpret_cast<const s16x8*>(qg + qrow * 64 + lg * 8);
  const s16x8 a1 = *reinterpret_cast<const s16x8*>(qg + qrow * 64 + 32 + lg * 8);
  f32x4 acc[4] = {};
#pragma unroll
  for (int ks2 = 0; ks2 < 2; ++ks2)
#pragma unroll
    for (int n = 0; n < 4; ++n) {
      s16x8 b = *reinterpret_cast<const s16x8*>(&Ts[(n * 16 + lr) * 72 + ks2 * 32 + lg * 8]);
      acc[n] = __builtin_amdgcn_mfma_f32_16x16x32_bf16(ks2 ? a1 : a0, b, acc[n], 0, 0, 0);
    }
  const size_t ob = ((size_t)(h * 64 + qh)) * 4096;
#pragma unroll
  for (int n = 0; n < 4; ++n) {
    s16x4 o;
#pragma unroll
    for (int r = 0; r < 4; ++r) o[r] = f2bf(acc[n][r] * LOG2E);
    *reinterpret_cast<s16x4*>(&rhT[ob + (size_t)(n * 16 + lr) * 64 + wave * 16 + lg * 4]) = o;
  }
}

// ---------------------------------------------------------------------------
// K2b: rel_w via U-GEMM + scatter, pre-scaled by log2e.
// ---------------------------------------------------------------------------
__global__ __launch_bounds__(256) void k_relw(const short* __restrict__ qg,
                                              const float* __restrict__ tab,
                                              short* __restrict__ rwg) {
  __shared__ short Ts[128 * 72];
  const int tid = threadIdx.x;
  const int wave = tid >> 6, lane = tid & 63, lr = lane & 15, lg = lane >> 4;
  const int h = blockIdx.x >> 6, qh = blockIdx.x & 63;
#pragma unroll
  for (int it = 0; it < 8; ++it) {
    int e = tid + 256 * it;
    int row = e >> 4, c4 = (e & 15) * 4;  // row = d
    s16x4 p = {0, 0, 0, 0};
    if (row < 127) {
      fvec4 v = *reinterpret_cast<const fvec4*>(tab + (size_t)row * 64 + c4);
      p[0] = f2bf(v[0]); p[1] = f2bf(v[1]); p[2] = f2bf(v[2]); p[3] = f2bf(v[3]);
    }
    *reinterpret_cast<s16x4*>(&Ts[row * 72 + c4]) = p;
  }
  __syncthreads();
  const size_t qrow = (size_t)h * N + qh * 64 + wave * 16 + lr;
  const s16x8 a0 = *reinterpret_cast<const s16x8*>(qg + qrow * 64 + lg * 8);
  const s16x8 a1 = *reinterpret_cast<const s16x8*>(qg + qrow * 64 + 32 + lg * 8);
  f32x4 acc[8] = {};
#pragma unroll
  for (int ks2 = 0; ks2 < 2; ++ks2)
#pragma unroll
    for (int n = 0; n < 8; ++n) {
      s16x8 b = *reinterpret_cast<const s16x8*>(&Ts[(n * 16 + lr) * 72 + ks2 * 32 + lg * 8]);
      acc[n] = __builtin_amdgcn_mfma_f32_16x16x32_bf16(ks2 ? a1 : a0, b, acc[n], 0, 0, 0);
    }
  const size_t ob = ((size_t)h * N + qh * 64) * 64;
#pragma unroll
  for (int n = 0; n < 8; ++n) {
    int d = n * 16 + lr;
#pragma unroll
    for (int r = 0; r < 4; ++r) {
      int qw = wave * 16 + lg * 4 + r;
      int kw = qw + 63 - d;
      if ((unsigned)kw < 64u) rwg[ob + (size_t)qw * 64 + kw] = f2bf(acc[n][r] * LOG2E);
    }
  }
}

// ---------------------------------------------------------------------------
// K3: flash attention v8.  Barrier-free, 48KB LDS (3 blocks/CU via LDS).
// Per-wave region (12KB): K dbuf @0/@4096 (32 rows x 128B each),
// V single-buf @8192 (32 rows x 128B; row r = {V^T[c=r][32 keys], V^T[c=r+32]}).
// V WAR guard: ds_read V -> lgkmcnt(0) -> STAGE_V(next).  Counted vmcnt(6).
// Softmax: p = exp2(sa + rh + rw)  (scales folded upstream).
// launch_bounds(256,2): the (256,3) VGPR cap spilled acc to scratch (r7).
// ---------------------------------------------------------------------------
#define QG_BLOCK(QB0, QB1, QB2, QB3, RW, RH2, ACC0, ACC1, LA, LB)              \
  do {                                                                         \
    f32x16 sa = {};                                                            \
    __builtin_amdgcn_s_setprio(1);                                             \
    sa = __builtin_amdgcn_mfma_f32_32x32x16_bf16(kf0, QB0, sa, 0, 0, 0);       \
    sa = __builtin_amdgcn_mfma_f32_32x32x16_bf16(kf1, QB1, sa, 0, 0, 0);       \
    sa = __builtin_amdgcn_mfma_f32_32x32x16_bf16(kf2, QB2, sa, 0, 0, 0);       \
    sa = __builtin_amdgcn_mfma_f32_32x32x16_bf16(kf3, QB3, sa, 0, 0, 0);       \
    __builtin_amdgcn_s_setprio(0);                                             \
    float p[16];                                                               \
    _Pragma("unroll")                                                          \
    for (int reg = 0; reg < 16; ++reg)                                         \
      p[reg] = ex2(sa[reg] + RH2 + RW[reg]);                                   \
    float t0 = (p[0] + p[1]) + (p[2] + p[3]);                                  \
    float t1 = (p[4] + p[5]) + (p[6] + p[7]);                                  \
    float t2 = (p[8] + p[9]) + (p[10] + p[11]);                                \
    float t3 = (p[12] + p[13]) + (p[14] + p[15]);                              \
    LA += t0 + t1;                                                             \
    LB += t2 + t3;                                                             \
    unsigned w00 = cvt_pk_bf16(p[0], p[1]),   w01 = cvt_pk_bf16(p[2], p[3]);   \
    unsigned w10 = cvt_pk_bf16(p[4], p[5]),   w11 = cvt_pk_bf16(p[6], p[7]);   \
    unsigned w20 = cvt_pk_bf16(p[8], p[9]),   w21 = cvt_pk_bf16(p[10], p[11]); \
    unsigned w30 = cvt_pk_bf16(p[12], p[13]), w31 = cvt_pk_bf16(p[14], p[15]); \
    asm("v_permlane32_swap_b32 %0, %1" : "+v"(w00), "+v"(w10));                \
    asm("v_permlane32_swap_b32 %0, %1" : "+v"(w01), "+v"(w11));                \
    asm("v_permlane32_swap_b32 %0, %1" : "+v"(w20), "+v"(w30));                \
    asm("v_permlane32_swap_b32 %0, %1" : "+v"(w21), "+v"(w31));                \
    u32x4 u0 = {w00, w01, w10, w11};                                           \
    u32x4 u1 = {w20, w21, w30, w31};                                           \
    s16x8 pa0 = __builtin_bit_cast(s16x8, u0);                                 \
    s16x8 pa1 = __builtin_bit_cast(s16x8, u1);                                 \
    __builtin_amdgcn_s_setprio(1);                                             \
    ACC0 = __builtin_amdgcn_mfma_f32_32x32x16_bf16(pa0, vf0, ACC0, 0, 0, 0);   \
    ACC0 = __builtin_amdgcn_mfma_f32_32x32x16_bf16(pa1, vf2, ACC0, 0, 0, 0);   \
    ACC1 = __builtin_amdgcn_mfma_f32_32x32x16_bf16(pa0, vf1, ACC1, 0, 0, 0);   \
    ACC1 = __builtin_amdgcn_mfma_f32_32x32x16_bf16(pa1, vf3, ACC1, 0, 0, 0);   \
    __builtin_amdgcn_s_setprio(0);                                             \
  } while (0)

// read K(i) from kbuf, V(i) from single V buf; then WAR-guard + stage V(NEXT)
#define FLASH_BODY(KBUFOFF, STAGE_V_NEXT, RHU0, RHU1)                          \
  do {                                                                         \
    const char* kb = wb + (KBUFOFF);                                           \
    s16x8 kf0 = *reinterpret_cast<const s16x8*>(kb + kco0);                    \
    s16x8 kf1 = *reinterpret_cast<const s16x8*>(kb + kco1);                    \
    s16x8 kf2 = *reinterpret_cast<const s16x8*>(kb + kco2);                    \
    s16x8 kf3 = *reinterpret_cast<const s16x8*>(kb + kco3);                    \
    s16x8 vf0 = *reinterpret_cast<const s16x8*>(wb + vco0);                    \
    s16x8 vf1 = *reinterpret_cast<const s16x8*>(wb + vco1);                    \
    s16x8 vf2 = *reinterpret_cast<const s16x8*>(wb + vco2);                    \
    s16x8 vf3 = *reinterpret_cast<const s16x8*>(wb + vco3);                    \
    asm volatile("s_waitcnt lgkmcnt(0)" ::: "memory");                         \
    __builtin_amdgcn_sched_barrier(0);                                         \
    STAGE_V_NEXT;                                                              \
    const float rh20 = bf2f((short)(RHU0));                                    \
    const float rh21 = bf2f((short)(RHU1));                                    \
    QG_BLOCK(qb00, qb01, qb02, qb03, rw0, rh20, acc00, acc01, la0, lb0);       \
    QG_BLOCK(qb10, qb11, qb12, qb13, rw1, rh21, acc10, acc11, la1, lb1);       \
  } while (0)

__global__ __launch_bounds__(256, 2) void k_flash(const short* __restrict__ qg,
                                                  const short* __restrict__ kg,
                                                  const short* __restrict__ vTg,
                                                  const short* __restrict__ rhTg,
                                                  const short* __restrict__ rwg,
                                                  short* __restrict__ aprime) {
  __shared__ __align__(16) char lds[49152];
  const int tid = threadIdx.x;
  const int wave = tid >> 6, lane = tid & 63;
  const int ql = lane & 31, hi = lane >> 5;
  const int kt2 = wave & 1, kh2 = wave >> 1;
  const int bid = blockIdx.x;
  const int id = (bid & 7) * 96 + (bid >> 3);  // bijective XCD swizzle (768%8==0)
  const int h = id >> 6, qt = id & 63;
  const int i0 = qt * 64;

  // Q fragments in registers
  const short* q0p = qg + ((size_t)h * N + i0 + ql) * 64 + hi * 8;
  const short* q1p = q0p + 32 * 64;
  const s16x8 qb00 = *reinterpret_cast<const s16x8*>(q0p);
  const s16x8 qb01 = *reinterpret_cast<const s16x8*>(q0p + 16);
  const s16x8 qb02 = *reinterpret_cast<const s16x8*>(q0p + 32);
  const s16x8 qb03 = *reinterpret_cast<const s16x8*>(q0p + 48);
  const s16x8 qb10 = *reinterpret_cast<const s16x8*>(q1p);
  const s16x8 qb11 = *reinterpret_cast<const s16x8*>(q1p + 16);
  const s16x8 qb12 = *reinterpret_cast<const s16x8*>(q1p + 32);
  const s16x8 qb13 = *reinterpret_cast<const s16x8*>(q1p + 48);

  // rel_w preload (already log2e-scaled by producer)
  f32x16 rw0, rw1;
  {
    const short* rwp0 = rwg + ((size_t)h * N + i0 + ql) * 64 + kh2 * 32 + hi * 4;
    const short* rwp1 = rwp0 + 32 * 64;
#pragma unroll
    for (int reg = 0; reg < 16; ++reg) {
      int o = (reg & 3) + 8 * (reg >> 2);
      rw0[reg] = bf2f(rwp0[o]);
      rw1[reg] = bf2f(rwp1[o]);
    }
  }
  const short* rhp = rhTg + ((size_t)(h * 64 + qt)) * 4096;

  // own-slice staging offsets (inverse-swizzled)
  const int kbrow = kt2 * 64 + kh2 * 32;   // wave's first key
  int koff[4], voff[4];
#pragma unroll
  for (int it = 0; it < 4; ++it) {
    int c = it * 64 + lane;
    int row = c >> 3, pos = c & 7, s = pos ^ (row & 7);
    koff[it] = (kbrow + row) * 128 + s * 16;
  }
#pragma unroll
  for (int it = 0; it < 4; ++it) {
    int c = it * 64 + lane;
    int r = c >> 3, pos = c & 7, s = pos ^ (r & 7);
    voff[it] = (r + ((s >> 2) << 5)) * 8192 + (kbrow + ((s & 3) << 3)) * 2;
  }
  const char* kgb = (const char*)kg + (size_t)h * N * 128;
  const char* vgb = (const char*)vTg + (size_t)h * 64 * 8192;
  char* wb = lds + wave * 12288;   // K0 @0, K1 @4096, V @8192

  auto STAGE_K = [&](int i, int buf) {
    const char* kp = kgb + (size_t)i * 16384;
    char* lp = wb + buf * 4096;
#pragma unroll
    for (int it = 0; it < 4; ++it) gload16(kp + koff[it], lp + it * 1024);
  };
  auto STAGE_V = [&](int i) {
    const char* vp = vgb + (size_t)i * 256;
    char* lp = wb + 8192;
#pragma unroll
    for (int it = 0; it < 4; ++it) gload16(vp + voff[it], lp + it * 1024);
  };

  // fragment read offsets (within wave region)
  const int swzq = (ql & 7) << 4;
  const int kco0 = ql * 128 + ((0 * 32 + hi * 16) ^ swzq);
  const int kco1 = ql * 128 + ((1 * 32 + hi * 16) ^ swzq);
  const int kco2 = ql * 128 + ((2 * 32 + hi * 16) ^ swzq);
  const int kco3 = ql * 128 + ((3 * 32 + hi * 16) ^ swzq);
  const int vco0 = 8192 + ql * 128 + ((0 * 64 + 0 * 32 + hi * 16) ^ swzq);  // ks0 ct0
  const int vco1 = 8192 + ql * 128 + ((1 * 64 + 0 * 32 + hi * 16) ^ swzq);  // ks0 ct1
  const int vco2 = 8192 + ql * 128 + ((0 * 64 + 1 * 32 + hi * 16) ^ swzq);  // ks1 ct0
  const int vco3 = 8192 + ql * 128 + ((1 * 64 + 1 * 32 + hi * 16) ^ swzq);  // ks1 ct1

  f32x16 acc00 = {}, acc01 = {}, acc10 = {}, acc11 = {};
  float la0 = 0.f, lb0 = 0.f, la1 = 0.f, lb1 = 0.f;

  // prologue: K(0) + rh(0) + V(0) -> 10 vmem in flight
  STAGE_K(0, 0);
  unsigned short rA0 = (unsigned short)rhp[(size_t)kt2 * 64 + ql];
  unsigned short rA1 = (unsigned short)rhp[(size_t)kt2 * 64 + 32 + ql];
  STAGE_V(0);
  unsigned short rB0 = 0, rB1 = 0;

  for (int ii = 0; ii < 16; ++ii) {
    const int i = 2 * ii;
    // even iter: K from buf0; prefetch K(i+1)->buf1, rh(i+1); V(i+1) staged
    // inside FLASH_BODY after the V reads retire.
    STAGE_K(i + 1, 1);
    rB0 = (unsigned short)rhp[(size_t)((i + 1) * 2 + kt2) * 64 + ql];
    rB1 = (unsigned short)rhp[(size_t)((i + 1) * 2 + kt2) * 64 + 32 + ql];
    asm volatile("s_waitcnt vmcnt(6)" ::: "memory");  // K(i), rh(i), V(i) landed
    __builtin_amdgcn_sched_barrier(0);
    FLASH_BODY(0, STAGE_V(i + 1), rA0, rA1);
    // odd iter
    if (i + 2 < 32) {
      STAGE_K(i + 2, 0);
      rA0 = (unsigned short)rhp[(size_t)((i + 2) * 2 + kt2) * 64 + ql];
      rA1 = (unsigned short)rhp[(size_t)((i + 2) * 2 + kt2) * 64 + 32 + ql];
      asm volatile("s_waitcnt vmcnt(6)" ::: "memory");
      __builtin_amdgcn_sched_barrier(0);
      FLASH_BODY(4096, STAGE_V(i + 2), rB0, rB1);
    } else {
      asm volatile("s_waitcnt vmcnt(0)" ::: "memory");
      __builtin_amdgcn_sched_barrier(0);
      FLASH_BODY(4096, (void)0, rB0, rB1);
    }
  }

  // ---- epilogue: cross-wave reduction of l and O ----
  __syncthreads();   // waves skewed; sync before LDS reuse
  float l0 = la0 + lb0, l1 = la1 + lb1;
  l0 += __shfl_xor(l0, 32);
  l1 += __shfl_xor(l1, 32);
  float* LS = (float*)lds;               // [4 waves][64 q] @0 (1KB)
  if (lane < 32) {
    LS[wave * 64 + ql] = l0;
    LS[wave * 64 + 32 + ql] = l1;
  }
  __syncthreads();
  const int eq = tid >> 2;               // q row 0..63
  const int cq = (tid & 3) * 8;          // col chunk within 32-col half
  float inv = 1.0f / (LS[eq] + LS[64 + eq] + LS[128 + eq] + LS[192 + eq]);
  float* OF = (float*)(lds + 4096);      // [4 waves][64 q][32 c] per pass (32KB)
  const size_t obase = (size_t)(i0 + eq) * 2304 + h * 64;

#pragma unroll
  for (int ct = 0; ct < 2; ++ct) {
    __syncthreads();
    const f32x16& a0 = ct ? acc01 : acc00;   // q-group 0
    const f32x16& a1 = ct ? acc11 : acc10;   // q-group 1
#pragma unroll
    for (int reg = 0; reg < 16; ++reg) {
      int qr = (reg & 3) + 8 * (reg >> 2) + 4 * hi;
      int sw = (qr & 3) << 3;
      OF[wave * 2048 + qr * 32 + (ql ^ sw)] = a0[reg];
      OF[wave * 2048 + (32 + qr) * 32 + (ql ^ sw)] = a1[reg];
    }
    __syncthreads();
    float osum[8];
#pragma unroll
    for (int j = 0; j < 8; ++j) {
      int cs = (cq + j) ^ ((eq & 3) << 3);
      osum[j] = OF[eq * 32 + cs] + OF[2048 + eq * 32 + cs] +
                OF[4096 + eq * 32 + cs] + OF[6144 + eq * 32 + cs];
    }
    s16x8 h8, l8;
#pragma unroll
    for (int j = 0; j < 8; ++j) {
      float o = osum[j] * inv;
      short oh = f2bf(o);
      h8[j] = oh;
      l8[j] = f2bf(o - bf2f(oh));
    }
    size_t ob2 = obase + ct * 32 + cq;
    *reinterpret_cast<s16x8*>(&aprime[ob2]) = h8;
    *reinterpret_cast<s16x8*>(&aprime[ob2 + 768]) = h8;
    *reinterpret_cast<s16x8*>(&aprime[ob2 + 1536]) = l8;
  }
}

// ---------------------------------------------------------------------------
extern "C" void kernel_launch(void* const* d_in, const int* in_sizes, int n_in,
                              void* d_out, int out_size, void* d_ws, size_t ws_size,
                              hipStream_t stream) {
  const float* x      = (const float*)d_in[0];
  const float* w_qkv  = (const float*)d_in[1];
  const float* b_qkv  = (const float*)d_in[2];
  const float* lora_A = (const float*)d_in[3];
  const float* lora_B = (const float*)d_in[4];
  const float* w_proj = (const float*)d_in[5];
  const float* b_proj = (const float*)d_in[6];
  const float* rel_h  = (const float*)d_in[7];
  const float* rel_w  = (const float*)d_in[8];
  float* out = (float*)d_out;

  char* ws = (char*)d_ws;
  short* weff   = (short*)(ws + 0);           // dead before flash
  short* xb     = (short*)(ws + 3538944);     // dead before flash
  short* vg     = (short*)(ws + 9830400);     // dead before flash
  short* aprime = (short*)(ws + 0);           // overlays the above
  short* qg     = (short*)(ws + 18874368);
  short* kg     = (short*)(ws + 25165824);
  short* vTg    = (short*)(ws + 31457280);
  short* rhT    = (short*)(ws + 37748736);
  short* rwg    = (short*)(ws + 44040192);
  short* wsp    = (short*)(ws + 50331648);    // -> total 53,870,592
  (void)ws_size; (void)in_sizes; (void)n_in; (void)out_size;

  k_weff<<<dim3((QKV * DIM + 255) / 256), dim3(256), 0, stream>>>(w_qkv, lora_A, lora_B, weff);
  k_x2bf<<<dim3(3072), dim3(256), 0, stream>>>(x, xb);
  k_wsplit<<<dim3(9, 768), dim3(256), 0, stream>>>(w_proj, wsp);
  k_gemm<12, 0, 128><<<dim3(32, 18), dim3(256), 0, stream>>>(xb, weff, b_qkv, qg, kg, vg, nullptr);
  k_vT<<<dim3(64, NH), dim3(256), 0, stream>>>(vg, vTg);
  k_relh<<<dim3(NH * 64), dim3(256), 0, stream>>>(qg, rel_h, rhT);
  k_relw<<<dim3(NH * 64), dim3(256), 0, stream>>>(qg, rel_w, rwg);
  k_flash<<<dim3(NH * 64), dim3(256), 0, stream>>>(qg, kg, vTg, rhT, rwg, aprime);
  k_gemm<36, 1, 64><<<dim3(64, 6), dim3(256), 0, stream>>>(aprime, wsp, b_proj, nullptr, nullptr, nullptr, out);
}

// Round 9
// 176.176 us; speedup vs baseline: 4.3675x; 2.2422x over previous
//
#include <hip/hip_runtime.h>
#include <stdint.h>

// ---------------------------------------------------------------------------
// Fused SAM-style attention block on MI355X (gfx950).  Round 9.
// Flash v9: NO LDS in main loop.  Each wave's K/V slice has zero cross-lane
// reuse (fragments == slice), so K and V load DIRECTLY global->VGPR:
// K reloaded after its last use (disjoint live ranges), V loaded just-in-time
// (~400cyc before PV).  No asm waitcnts -- compiler emits precise counted
// vmcnt for register loads.  sa is initialized to rh+rw via the MFMA C input.
// r7/r8 lesson: LDS-slimming restructures caused register spills (watch
// WRITE_SIZE); this drops the whole staging path instead.
// ---------------------------------------------------------------------------

typedef __attribute__((ext_vector_type(4))) float f32x4;
typedef __attribute__((ext_vector_type(16))) float f32x16;
typedef __attribute__((ext_vector_type(4))) float fvec4;
typedef __attribute__((ext_vector_type(8))) short s16x8;
typedef __attribute__((ext_vector_type(4))) short s16x4;
typedef __attribute__((ext_vector_type(4))) unsigned u32x4;

constexpr int NH  = 12;
constexpr int HD  = 64;
constexpr int DIM = 768;
constexpr int N   = 4096;
constexpr int QKV = 2304;
constexpr float LOG2E  = 1.4426950408889634f;
constexpr float SCALE2 = 0.125f * LOG2E;   // folded into kg at QKV epilogue

static __device__ __forceinline__ short f2bf(float f) {
  unsigned u = __builtin_bit_cast(unsigned, f);
  unsigned r = (u + 0x7FFFu + ((u >> 16) & 1u)) >> 16;  // RNE
  return (short)r;
}
static __device__ __forceinline__ float bf2f(short s) {
  unsigned u = ((unsigned)(unsigned short)s) << 16;
  return __builtin_bit_cast(float, u);
}
static __device__ __forceinline__ unsigned cvt_pk_bf16(float a, float b) {
  unsigned r;
  asm("v_cvt_pk_bf16_f32 %0, %1, %2" : "=v"(r) : "v"(a), "v"(b));
  return r;
}
static __device__ __forceinline__ float ex2(float x) {
  float r;
  asm("v_exp_f32 %0, %1" : "=v"(r) : "v"(x));
  return r;
}
static __device__ __forceinline__ void gload16(const void* g, void* l) {
  __builtin_amdgcn_global_load_lds(
      (const __attribute__((address_space(1))) void*)g,
      (__attribute__((address_space(3))) void*)l, 16, 0, 0);
}
static __device__ __forceinline__ void barrier_pre() {
  __builtin_amdgcn_s_barrier();
  __builtin_amdgcn_sched_barrier(0);
}
static __device__ __forceinline__ void barrier_post() {
  __builtin_amdgcn_sched_barrier(0);
  __builtin_amdgcn_s_barrier();
  __builtin_amdgcn_sched_barrier(0);
}

// ---------------------------------------------------------------------------
// K0: W_eff = w_qkv + lora_B @ lora_A  (bf16 out, [2304][768])
// ---------------------------------------------------------------------------
__global__ __launch_bounds__(256) void k_weff(const float* __restrict__ w_qkv,
                                              const float* __restrict__ lora_A,
                                              const float* __restrict__ lora_B,
                                              short* __restrict__ weff) {
  int e = blockIdx.x * 256 + threadIdx.x;
  if (e >= QKV * DIM) return;
  int r = e / DIM, c = e % DIM;
  float acc = w_qkv[e];
#pragma unroll
  for (int t = 0; t < 12; ++t) acc += lora_B[r * 12 + t] * lora_A[t * DIM + c];
  weff[e] = f2bf(acc);
}

// ---------------------------------------------------------------------------
// K0b: x fp32 -> bf16
// ---------------------------------------------------------------------------
__global__ __launch_bounds__(256) void k_x2bf(const float* __restrict__ x,
                                              short* __restrict__ xb) {
  int i = blockIdx.x * 256 + threadIdx.x;
  fvec4 v = *reinterpret_cast<const fvec4*>(x + (size_t)i * 4);
  s16x4 p;
  p[0] = f2bf(v[0]); p[1] = f2bf(v[1]); p[2] = f2bf(v[2]); p[3] = f2bf(v[3]);
  *reinterpret_cast<s16x4*>(xb + (size_t)i * 4) = p;
}

// ---------------------------------------------------------------------------
// K0c: w_proj -> split-bf16 B' [768][2304] = [Whi | Wlo | Whi]
// ---------------------------------------------------------------------------
__global__ __launch_bounds__(256) void k_wsplit(const float* __restrict__ w,
                                                short* __restrict__ ws) {
  int r = blockIdx.y;
  int kk = blockIdx.x * 256 + threadIdx.x;
  int blk = (kk >= 1536) ? 2 : (kk >= 768 ? 1 : 0);
  int c = kk - blk * 768;
  float wv = w[(size_t)r * 768 + c];
  short hi = f2bf(wv);
  ws[(size_t)r * 2304 + kk] = (blk == 1) ? f2bf(wv - bf2f(hi)) : hi;
}

// ---------------------------------------------------------------------------
// BMx128 MFMA GEMM, BK=64, double-buffered, counted vmcnt + raw barriers.
// MODE 0: qkv scatter (k scaled by SCALE2).  MODE 1: fp32 out + bias.
// ---------------------------------------------------------------------------
template <int KIT, int MODE, int BM>
__global__ __launch_bounds__(256, 2) void k_gemm(const short* __restrict__ A,
                                                 const short* __restrict__ B,
                                                 const float* __restrict__ bias,
                                                 short* __restrict__ qo,
                                                 short* __restrict__ ko,
                                                 short* __restrict__ vo,
                                                 float* __restrict__ outf) {
  constexpr int MFR = BM / 32;              // A m-frags per wave
  constexpr int BUFB = BM * 128 + 16384;    // bytes per buffer (A + B tiles)
  __shared__ __align__(16) char lds[2 * BUFB];
  const int tid = threadIdx.x;
  const int wave = tid >> 6, lane = tid & 63, lr = lane & 15, lg = lane >> 4;
  const int wr = wave >> 1, wc = wave & 1;
  const int i0 = blockIdx.x * BM, j0 = blockIdx.y * 128;
  const int LDA = KIT * 128;  // row bytes

  size_t offA[MFR], offB[4];
#pragma unroll
  for (int it = 0; it < MFR; ++it) {
    int c = it * 256 + tid;
    int row = c >> 3;
    offA[it] = (size_t)row * LDA + (((c & 7) << 4) ^ ((row & 7) << 4));
  }
#pragma unroll
  for (int it = 0; it < 4; ++it) {
    int c = it * 256 + tid;
    int row = c >> 3;
    offB[it] = (size_t)row * LDA + (((c & 7) << 4) ^ ((row & 7) << 4));
  }
  const char* Ab = (const char*)A + (size_t)i0 * LDA;
  const char* Bb = (const char*)B + (size_t)j0 * LDA;

  auto STAGE = [&](int kt, int b) {
    char* base = lds + b * BUFB;
    const size_t kadd = (size_t)kt * 128;
#pragma unroll
    for (int it = 0; it < MFR; ++it)
      gload16(Ab + kadd + offA[it], base + wave * 1024 + it * 4096);
#pragma unroll
    for (int it = 0; it < 4; ++it)
      gload16(Bb + kadd + offB[it], base + BM * 128 + wave * 1024 + it * 4096);
  };

  const int swz = (lr & 7) << 4;
  const int ab = (wr * (BM / 2) + lr) * 128 + ((lg * 16) ^ swz);
  const int bb = BM * 128 + (wc * 64 + lr) * 128 + ((lg * 16) ^ swz);

  f32x4 acc[MFR][4] = {};

  STAGE(0, 0);
  for (int kt = 0; kt < KIT; ++kt) {
    const int buf = kt & 1;
    if (kt + 1 < KIT) {
      STAGE(kt + 1, buf ^ 1);
      if constexpr (BM == 128)
        asm volatile("s_waitcnt vmcnt(8)" ::: "memory");
      else
        asm volatile("s_waitcnt vmcnt(6)" ::: "memory");
    } else {
      asm volatile("s_waitcnt vmcnt(0)" ::: "memory");
    }
    barrier_pre();
    const char* bufp = lds + buf * BUFB;
#pragma unroll
    for (int ks2 = 0; ks2 < 2; ++ks2) {
      s16x8 af[MFR], bf_[4];
#pragma unroll
      for (int m = 0; m < MFR; ++m)
        af[m] = *reinterpret_cast<const s16x8*>(bufp + ((ab + m * 2048) ^ (ks2 << 6)));
#pragma unroll
      for (int n = 0; n < 4; ++n)
        bf_[n] = *reinterpret_cast<const s16x8*>(bufp + ((bb + n * 2048) ^ (ks2 << 6)));
#pragma unroll
      for (int m = 0; m < MFR; ++m)
#pragma unroll
        for (int n = 0; n < 4; ++n)
          acc[m][n] = __builtin_amdgcn_mfma_f32_16x16x32_bf16(af[m], bf_[n], acc[m][n], 0, 0, 0);
    }
    barrier_post();
  }

  if constexpr (MODE == 0) {
    const int three = j0 / 768;
    const int head = ((j0 % 768) >> 6) + wc;
    const float osc = (three == 1) ? SCALE2 : 1.0f;  // fold SCALE*log2e into K
    short* dst = (three == 0) ? qo : ((three == 1) ? ko : vo);
#pragma unroll
    for (int n = 0; n < 4; ++n) {
      const int col = n * 16 + lr;
      const float bj = bias[j0 + wc * 64 + col];
#pragma unroll
      for (int m = 0; m < MFR; ++m)
#pragma unroll
        for (int r = 0; r < 4; ++r) {
          int i = i0 + wr * (BM / 2) + m * 16 + lg * 4 + r;
          dst[((size_t)head * N + i) * HD + col] = f2bf((acc[m][n][r] + bj) * osc);
        }
    }
  } else {
#pragma unroll
    for (int n = 0; n < 4; ++n) {
      const int j = j0 + wc * 64 + n * 16 + lr;
      const float bj = bias[j];
#pragma unroll
      for (int m = 0; m < MFR; ++m)
#pragma unroll
        for (int r = 0; r < 4; ++r) {
          int i = i0 + wr * (BM / 2) + m * 16 + lg * 4 + r;
          outf[(size_t)i * 768 + j] = acc[m][n][r] + bj;
        }
    }
  }
}

// ---------------------------------------------------------------------------
// K1b: vT[h][c][i] = v[h][i][c]
// ---------------------------------------------------------------------------
__global__ __launch_bounds__(256) void k_vT(const short* __restrict__ vg,
                                            short* __restrict__ vTg) {
  __shared__ short ts[64 * 72];
  const int tid = threadIdx.x;
  const int i0 = blockIdx.x * 64;
  const int h = blockIdx.y;
#pragma unroll
  for (int it = 0; it < 2; ++it) {
    int ch = tid + 256 * it;
    int row = ch >> 3, cc = (ch & 7) * 8;
    *reinterpret_cast<s16x8*>(&ts[row * 72 + cc]) =
        *reinterpret_cast<const s16x8*>(&vg[((size_t)h * N + i0 + row) * HD + cc]);
  }
  __syncthreads();
#pragma unroll
  for (int it = 0; it < 2; ++it) {
    int ch = tid + 256 * it;
    int c = ch >> 3, ii = (ch & 7) * 8;
    s16x8 o;
#pragma unroll
    for (int j = 0; j < 8; ++j) o[j] = ts[(ii + j) * 72 + c];
    *reinterpret_cast<s16x8*>(&vTg[((size_t)h * HD + c) * N + i0 + ii]) = o;
  }
}

// ---------------------------------------------------------------------------
// K2a: rel_h via MFMA, stored TRANSPOSED & pre-scaled by log2e:
// rhT[h][qh][kh][qw] = log2e * dot(q, tab[qh-kh+63])
// ---------------------------------------------------------------------------
__global__ __launch_bounds__(256) void k_relh(const short* __restrict__ qg,
                                              const float* __restrict__ tab,
                                              short* __restrict__ rhT) {
  __shared__ short Ts[64 * 72];
  const int tid = threadIdx.x;
  const int wave = tid >> 6, lane = tid & 63, lr = lane & 15, lg = lane >> 4;
  const int h = blockIdx.x >> 6, qh = blockIdx.x & 63;
#pragma unroll
  for (int it = 0; it < 4; ++it) {
    int e = tid + 256 * it;
    int row = e >> 4, c4 = (e & 15) * 4;  // row = kh
    fvec4 v = *reinterpret_cast<const fvec4*>(tab + (size_t)(qh + 63 - row) * 64 + c4);
    s16x4 p;
    p[0] = f2bf(v[0]); p[1] = f2bf(v[1]); p[2] = f2bf(v[2]); p[3] = f2bf(v[3]);
    *reinterpret_cast<s16x4*>(&Ts[row * 72 + c4]) = p;
  }
  __syncthreads();
  const size_t qrow = (size_t)h * N + qh * 64 + wave * 16 + lr;
  const s16x8 a0 = *reinterpret_cast<const s16x8*>(qg + qrow * 64 + lg * 8);
  const s16x8 a1 = *reinterpret_cast<const s16x8*>(qg + qrow * 64 + 32 + lg * 8);
  f32x4 acc[4] = {};
#pragma unroll
  for (int ks2 = 0; ks2 < 2; ++ks2)
#pragma unroll
    for (int n = 0; n < 4; ++n) {
      s16x8 b = *reinterpret_cast<const s16x8*>(&Ts[(n * 16 + lr) * 72 + ks2 * 32 + lg * 8]);
      acc[n] = __builtin_amdgcn_mfma_f32_16x16x32_bf16(ks2 ? a1 : a0, b, acc[n], 0, 0, 0);
    }
  const size_t ob = ((size_t)(h * 64 + qh)) * 4096;
#pragma unroll
  for (int n = 0; n < 4; ++n) {
    s16x4 o;
#pragma unroll
    for (int r = 0; r < 4; ++r) o[r] = f2bf(acc[n][r] * LOG2E);
    *reinterpret_cast<s16x4*>(&rhT[ob + (size_t)(n * 16 + lr) * 64 + wave * 16 + lg * 4]) = o;
  }
}

// ---------------------------------------------------------------------------
// K2b: rel_w via U-GEMM + scatter, pre-scaled by log2e.
// ---------------------------------------------------------------------------
__global__ __launch_bounds__(256) void k_relw(const short* __restrict__ qg,
                                              const float* __restrict__ tab,
                                              short* __restrict__ rwg) {
  __shared__ short Ts[128 * 72];
  const int tid = threadIdx.x;
  const int wave = tid >> 6, lane = tid & 63, lr = lane & 15, lg = lane >> 4;
  const int h = blockIdx.x >> 6, qh = blockIdx.x & 63;
#pragma unroll
  for (int it = 0; it < 8; ++it) {
    int e = tid + 256 * it;
    int row = e >> 4, c4 = (e & 15) * 4;  // row = d
    s16x4 p = {0, 0, 0, 0};
    if (row < 127) {
      fvec4 v = *reinterpret_cast<const fvec4*>(tab + (size_t)row * 64 + c4);
      p[0] = f2bf(v[0]); p[1] = f2bf(v[1]); p[2] = f2bf(v[2]); p[3] = f2bf(v[3]);
    }
    *reinterpret_cast<s16x4*>(&Ts[row * 72 + c4]) = p;
  }
  __syncthreads();
  const size_t qrow = (size_t)h * N + qh * 64 + wave * 16 + lr;
  const s16x8 a0 = *reinterpret_cast<const s16x8*>(qg + qrow * 64 + lg * 8);
  const s16x8 a1 = *reinterpret_cast<const s16x8*>(qg + qrow * 64 + 32 + lg * 8);
  f32x4 acc[8] = {};
#pragma unroll
  for (int ks2 = 0; ks2 < 2; ++ks2)
#pragma unroll
    for (int n = 0; n < 8; ++n) {
      s16x8 b = *reinterpret_cast<const s16x8*>(&Ts[(n * 16 + lr) * 72 + ks2 * 32 + lg * 8]);
      acc[n] = __builtin_amdgcn_mfma_f32_16x16x32_bf16(ks2 ? a1 : a0, b, acc[n], 0, 0, 0);
    }
  const size_t ob = ((size_t)h * N + qh * 64) * 64;
#pragma unroll
  for (int n = 0; n < 8; ++n) {
    int d = n * 16 + lr;
#pragma unroll
    for (int r = 0; r < 4; ++r) {
      int qw = wave * 16 + lg * 4 + r;
      int kw = qw + 63 - d;
      if ((unsigned)kw < 64u) rwg[ob + (size_t)qw * 64 + kw] = f2bf(acc[n][r] * LOG2E);
    }
  }
}

// ---------------------------------------------------------------------------
// K3: flash attention v9.  Waves = (kt2,kh2) own a disjoint 32-key slice of
// each 128-key double tile; all 64 q rows per wave in registers.
// K/V load DIRECTLY global->VGPR (fragments are 16B-contiguous in kg / vTg).
// No LDS, no barriers, no asm waits in the loop.  LDS (36.9KB) epilogue only.
// ---------------------------------------------------------------------------
__global__ __launch_bounds__(256, 2) void k_flash(const short* __restrict__ qg,
                                                  const short* __restrict__ kg,
                                                  const short* __restrict__ vTg,
                                                  const short* __restrict__ rhTg,
                                                  const short* __restrict__ rwg,
                                                  short* __restrict__ aprime) {
  __shared__ __align__(16) char lds[36864];
  const int tid = threadIdx.x;
  const int wave = tid >> 6, lane = tid & 63;
  const int ql = lane & 31, hi = lane >> 5;
  const int kt2 = wave & 1, kh2 = wave >> 1;
  const int bid = blockIdx.x;
  const int id = (bid & 7) * 96 + (bid >> 3);  // bijective XCD swizzle (768%8==0)
  const int h = id >> 6, qt = id & 63;
  const int i0 = qt * 64;

  // Q fragments in registers: qbG_c = Q[i0+G*32+ql][c*16 + hi*8 .. +8]
  const short* q0p = qg + ((size_t)h * N + i0 + ql) * 64 + hi * 8;
  const short* q1p = q0p + 32 * 64;
  const s16x8 qb00 = *reinterpret_cast<const s16x8*>(q0p);
  const s16x8 qb01 = *reinterpret_cast<const s16x8*>(q0p + 16);
  const s16x8 qb02 = *reinterpret_cast<const s16x8*>(q0p + 32);
  const s16x8 qb03 = *reinterpret_cast<const s16x8*>(q0p + 48);
  const s16x8 qb10 = *reinterpret_cast<const s16x8*>(q1p);
  const s16x8 qb11 = *reinterpret_cast<const s16x8*>(q1p + 16);
  const s16x8 qb12 = *reinterpret_cast<const s16x8*>(q1p + 32);
  const s16x8 qb13 = *reinterpret_cast<const s16x8*>(q1p + 48);

  // rel_w preload (log2e-scaled by producer): rwG[reg]
  f32x16 rw0, rw1;
  {
    const short* rwp0 = rwg + ((size_t)h * N + i0 + ql) * 64 + kh2 * 32 + hi * 4;
    const short* rwp1 = rwp0 + 32 * 64;
#pragma unroll
    for (int reg = 0; reg < 16; ++reg) {
      int o = (reg & 3) + 8 * (reg >> 2);
      rw0[reg] = bf2f(rwp0[o]);
      rw1[reg] = bf2f(rwp1[o]);
    }
  }
  const short* rhp = rhTg + ((size_t)(h * 64 + qt)) * 4096;

  const int kbrow = kt2 * 64 + kh2 * 32;   // wave's first key within dbl tile
  // K: kf_c = K[key = t*128 + kbrow + ql][d = c*16 + hi*8 .. +8]
  const short* kb = kg + (((size_t)h * N + kbrow + ql) * 64 + hi * 8);
  // V: vf(ks,ct) = V^T[c = ct*32+ql][key = t*128 + kbrow + ks*16 + hi*8 .. +8]
  const short* vb0 = vTg + (((size_t)h * 64 + ql) * (size_t)N + kbrow + hi * 8);
  const short* vb1 = vb0 + (size_t)32 * N;

  f32x16 acc00 = {}, acc01 = {}, acc10 = {}, acc11 = {};
  float la0 = 0.f, lb0 = 0.f, la1 = 0.f, lb1 = 0.f;

  // prologue: K(0), rh(0)
  s16x8 kf0 = *reinterpret_cast<const s16x8*>(kb);
  s16x8 kf1 = *reinterpret_cast<const s16x8*>(kb + 16);
  s16x8 kf2 = *reinterpret_cast<const s16x8*>(kb + 32);
  s16x8 kf3 = *reinterpret_cast<const s16x8*>(kb + 48);
  float rh20 = bf2f(rhp[(size_t)kt2 * 64 + ql]);
  float rh21 = bf2f(rhp[(size_t)kt2 * 64 + 32 + ql]);

  for (int t = 0; t < 32; ++t) {
    // V just-in-time (used ~softmax-latency later at PV)
    const size_t vo = (size_t)t * 128;
    s16x8 vf00 = *reinterpret_cast<const s16x8*>(vb0 + vo);        // ks0 ct0
    s16x8 vf01 = *reinterpret_cast<const s16x8*>(vb0 + vo + 16);   // ks1 ct0
    s16x8 vf10 = *reinterpret_cast<const s16x8*>(vb1 + vo);        // ks0 ct1
    s16x8 vf11 = *reinterpret_cast<const s16x8*>(vb1 + vo + 16);   // ks1 ct1

    // sa init = rh + rw (folded into MFMA C input)
    f32x16 sa0, sa1;
#pragma unroll
    for (int r = 0; r < 16; ++r) sa0[r] = rh20 + rw0[r];
#pragma unroll
    for (int r = 0; r < 16; ++r) sa1[r] = rh21 + rw1[r];

    __builtin_amdgcn_s_setprio(1);
    sa0 = __builtin_amdgcn_mfma_f32_32x32x16_bf16(kf0, qb00, sa0, 0, 0, 0);
    sa0 = __builtin_amdgcn_mfma_f32_32x32x16_bf16(kf1, qb01, sa0, 0, 0, 0);
    sa0 = __builtin_amdgcn_mfma_f32_32x32x16_bf16(kf2, qb02, sa0, 0, 0, 0);
    sa0 = __builtin_amdgcn_mfma_f32_32x32x16_bf16(kf3, qb03, sa0, 0, 0, 0);
    sa1 = __builtin_amdgcn_mfma_f32_32x32x16_bf16(kf0, qb10, sa1, 0, 0, 0);
    sa1 = __builtin_amdgcn_mfma_f32_32x32x16_bf16(kf1, qb11, sa1, 0, 0, 0);
    sa1 = __builtin_amdgcn_mfma_f32_32x32x16_bf16(kf2, qb12, sa1, 0, 0, 0);
    sa1 = __builtin_amdgcn_mfma_f32_32x32x16_bf16(kf3, qb13, sa1, 0, 0, 0);
    __builtin_amdgcn_s_setprio(0);

    // K(t+1) reload (kf dead after QK); rh(t+1)
    const int tn = (t + 1 < 32) ? t + 1 : 31;
    const size_t kon = (size_t)tn * 128 * 64;
    kf0 = *reinterpret_cast<const s16x8*>(kb + kon);
    kf1 = *reinterpret_cast<const s16x8*>(kb + kon + 16);
    kf2 = *reinterpret_cast<const s16x8*>(kb + kon + 32);
    kf3 = *reinterpret_cast<const s16x8*>(kb + kon + 48);
    const float rh20n = bf2f(rhp[(size_t)(tn * 2 + kt2) * 64 + ql]);
    const float rh21n = bf2f(rhp[(size_t)(tn * 2 + kt2) * 64 + 32 + ql]);

    // softmax group0
    float p0[16], p1[16];
#pragma unroll
    for (int r = 0; r < 16; ++r) p0[r] = ex2(sa0[r]);
#pragma unroll
    for (int r = 0; r < 16; ++r) p1[r] = ex2(sa1[r]);
    la0 += ((p0[0] + p0[1]) + (p0[2] + p0[3])) + ((p0[4] + p0[5]) + (p0[6] + p0[7]));
    lb0 += ((p0[8] + p0[9]) + (p0[10] + p0[11])) + ((p0[12] + p0[13]) + (p0[14] + p0[15]));
    la1 += ((p1[0] + p1[1]) + (p1[2] + p1[3])) + ((p1[4] + p1[5]) + (p1[6] + p1[7]));
    lb1 += ((p1[8] + p1[9]) + (p1[10] + p1[11])) + ((p1[12] + p1[13]) + (p1[14] + p1[15]));

    unsigned a00 = cvt_pk_bf16(p0[0], p0[1]),   a01 = cvt_pk_bf16(p0[2], p0[3]);
    unsigned a10 = cvt_pk_bf16(p0[4], p0[5]),   a11 = cvt_pk_bf16(p0[6], p0[7]);
    unsigned a20 = cvt_pk_bf16(p0[8], p0[9]),   a21 = cvt_pk_bf16(p0[10], p0[11]);
    unsigned a30 = cvt_pk_bf16(p0[12], p0[13]), a31 = cvt_pk_bf16(p0[14], p0[15]);
    asm("v_permlane32_swap_b32 %0, %1" : "+v"(a00), "+v"(a10));
    asm("v_permlane32_swap_b32 %0, %1" : "+v"(a01), "+v"(a11));
    asm("v_permlane32_swap_b32 %0, %1" : "+v"(a20), "+v"(a30));
    asm("v_permlane32_swap_b32 %0, %1" : "+v"(a21), "+v"(a31));
    u32x4 ua0 = {a00, a01, a10, a11};
    u32x4 ua1 = {a20, a21, a30, a31};
    s16x8 pa00 = __builtin_bit_cast(s16x8, ua0);
    s16x8 pa01 = __builtin_bit_cast(s16x8, ua1);

    unsigned b00 = cvt_pk_bf16(p1[0], p1[1]),   b01 = cvt_pk_bf16(p1[2], p1[3]);
    unsigned b10 = cvt_pk_bf16(p1[4], p1[5]),   b11 = cvt_pk_bf16(p1[6], p1[7]);
    unsigned b20 = cvt_pk_bf16(p1[8], p1[9]),   b21 = cvt_pk_bf16(p1[10], p1[11]);
    unsigned b30 = cvt_pk_bf16(p1[12], p1[13]), b31 = cvt_pk_bf16(p1[14], p1[15]);
    asm("v_permlane32_swap_b32 %0, %1" : "+v"(b00), "+v"(b10));
    asm("v_permlane32_swap_b32 %0, %1" : "+v"(b01), "+v"(b11));
    asm("v_permlane32_swap_b32 %0, %1" : "+v"(b20), "+v"(b30));
    asm("v_permlane32_swap_b32 %0, %1" : "+v"(b21), "+v"(b31));
    u32x4 ub0 = {b00, b01, b10, b11};
    u32x4 ub1 = {b20, b21, b30, b31};
    s16x8 pa10 = __builtin_bit_cast(s16x8, ub0);
    s16x8 pa11 = __builtin_bit_cast(s16x8, ub1);

    // PV
    __builtin_amdgcn_s_setprio(1);
    acc00 = __builtin_amdgcn_mfma_f32_32x32x16_bf16(pa00, vf00, acc00, 0, 0, 0);
    acc00 = __builtin_amdgcn_mfma_f32_32x32x16_bf16(pa01, vf01, acc00, 0, 0, 0);
    acc01 = __builtin_amdgcn_mfma_f32_32x32x16_bf16(pa00, vf10, acc01, 0, 0, 0);
    acc01 = __builtin_amdgcn_mfma_f32_32x32x16_bf16(pa01, vf11, acc01, 0, 0, 0);
    acc10 = __builtin_amdgcn_mfma_f32_32x32x16_bf16(pa10, vf00, acc10, 0, 0, 0);
    acc10 = __builtin_amdgcn_mfma_f32_32x32x16_bf16(pa11, vf01, acc10, 0, 0, 0);
    acc11 = __builtin_amdgcn_mfma_f32_32x32x16_bf16(pa10, vf10, acc11, 0, 0, 0);
    acc11 = __builtin_amdgcn_mfma_f32_32x32x16_bf16(pa11, vf11, acc11, 0, 0, 0);
    __builtin_amdgcn_s_setprio(0);

    rh20 = rh20n;
    rh21 = rh21n;
  }

  // ---- epilogue: cross-wave reduction of l and O (r8's, proven) ----
  __syncthreads();
  float l0 = la0 + lb0, l1 = la1 + lb1;
  l0 += __shfl_xor(l0, 32);
  l1 += __shfl_xor(l1, 32);
  float* LS = (float*)lds;               // [4 waves][64 q] @0 (1KB)
  if (lane < 32) {
    LS[wave * 64 + ql] = l0;
    LS[wave * 64 + 32 + ql] = l1;
  }
  __syncthreads();
  const int eq = tid >> 2;               // q row 0..63
  const int cq = (tid & 3) * 8;          // col chunk within 32-col half
  float inv = 1.0f / (LS[eq] + LS[64 + eq] + LS[128 + eq] + LS[192 + eq]);
  float* OF = (float*)(lds + 4096);      // [4 waves][64 q][32 c] per pass (32KB)
  const size_t obase = (size_t)(i0 + eq) * 2304 + h * 64;

#pragma unroll
  for (int ct = 0; ct < 2; ++ct) {
    __syncthreads();
    const f32x16& a0 = ct ? acc01 : acc00;   // q-group 0
    const f32x16& a1 = ct ? acc11 : acc10;   // q-group 1
#pragma unroll
    for (int reg = 0; reg < 16; ++reg) {
      int qr = (reg & 3) + 8 * (reg >> 2) + 4 * hi;
      int sw = (qr & 3) << 3;
      OF[wave * 2048 + qr * 32 + (ql ^ sw)] = a0[reg];
      OF[wave * 2048 + (32 + qr) * 32 + (ql ^ sw)] = a1[reg];
    }
    __syncthreads();
    float osum[8];
#pragma unroll
    for (int j = 0; j < 8; ++j) {
      int cs = (cq + j) ^ ((eq & 3) << 3);
      osum[j] = OF[eq * 32 + cs] + OF[2048 + eq * 32 + cs] +
                OF[4096 + eq * 32 + cs] + OF[6144 + eq * 32 + cs];
    }
    s16x8 h8, l8;
#pragma unroll
    for (int j = 0; j < 8; ++j) {
      float o = osum[j] * inv;
      short oh = f2bf(o);
      h8[j] = oh;
      l8[j] = f2bf(o - bf2f(oh));
    }
    size_t ob2 = obase + ct * 32 + cq;
    *reinterpret_cast<s16x8*>(&aprime[ob2]) = h8;
    *reinterpret_cast<s16x8*>(&aprime[ob2 + 768]) = h8;
    *reinterpret_cast<s16x8*>(&aprime[ob2 + 1536]) = l8;
  }
}

// ---------------------------------------------------------------------------
extern "C" void kernel_launch(void* const* d_in, const int* in_sizes, int n_in,
                              void* d_out, int out_size, void* d_ws, size_t ws_size,
                              hipStream_t stream) {
  const float* x      = (const float*)d_in[0];
  const float* w_qkv  = (const float*)d_in[1];
  const float* b_qkv  = (const float*)d_in[2];
  const float* lora_A = (const float*)d_in[3];
  const float* lora_B = (const float*)d_in[4];
  const float* w_proj = (const float*)d_in[5];
  const float* b_proj = (const float*)d_in[6];
  const float* rel_h  = (const float*)d_in[7];
  const float* rel_w  = (const float*)d_in[8];
  float* out = (float*)d_out;

  char* ws = (char*)d_ws;
  short* weff   = (short*)(ws + 0);           // dead before flash
  short* xb     = (short*)(ws + 3538944);     // dead before flash
  short* vg     = (short*)(ws + 9830400);     // dead before flash
  short* aprime = (short*)(ws + 0);           // overlays the above
  short* qg     = (short*)(ws + 18874368);
  short* kg     = (short*)(ws + 25165824);
  short* vTg    = (short*)(ws + 31457280);
  short* rhT    = (short*)(ws + 37748736);
  short* rwg    = (short*)(ws + 44040192);
  short* wsp    = (short*)(ws + 50331648);    // -> total 53,870,592
  (void)ws_size; (void)in_sizes; (void)n_in; (void)out_size;

  k_weff<<<dim3((QKV * DIM + 255) / 256), dim3(256), 0, stream>>>(w_qkv, lora_A, lora_B, weff);
  k_x2bf<<<dim3(3072), dim3(256), 0, stream>>>(x, xb);
  k_wsplit<<<dim3(9, 768), dim3(256), 0, stream>>>(w_proj, wsp);
  k_gemm<12, 0, 128><<<dim3(32, 18), dim3(256), 0, stream>>>(xb, weff, b_qkv, qg, kg, vg, nullptr);
  k_vT<<<dim3(64, NH), dim3(256), 0, stream>>>(vg, vTg);
  k_relh<<<dim3(NH * 64), dim3(256), 0, stream>>>(qg, rel_h, rhT);
  k_relw<<<dim3(NH * 64), dim3(256), 0, stream>>>(qg, rel_w, rwg);
  k_flash<<<dim3(NH * 64), dim3(256), 0, stream>>>(qg, kg, vTg, rhT, rwg, aprime);
  k_gemm<36, 1, 64><<<dim3(64, 6), dim3(256), 0, stream>>>(aprime, wsp, b_proj, nullptr, nullptr, nullptr, out);
}

// Round 13
// 161.024 us; speedup vs baseline: 4.7785x; 1.0941x over previous
//
#include <hip/hip_runtime.h>
#include <stdint.h>

// ---------------------------------------------------------------------------
// Fused SAM-style attention block on MI355X (gfx950).  Round 13.
// Flash = r4's PROVEN __syncthreads-per-iteration loop (97.5us, correct by
// construction: syncthreads drains vmcnt -> cross-wave staging is safe)
// + the r7/r8-validated numerical folds (SCALE*log2e in kg, log2e in rel
// producers, softmax = ex2(sa+rh+rw)).  GEMMs = r5-r9's counted-vmcnt
// double-buffer (block-local barriers, proven).
// r6/r10/r11/r12 lesson: barrier-free cross-wave staging is a latent race
// (r12 NaN); that family is abandoned.
// ---------------------------------------------------------------------------

typedef __attribute__((ext_vector_type(4))) float f32x4;
typedef __attribute__((ext_vector_type(16))) float f32x16;
typedef __attribute__((ext_vector_type(4))) float fvec4;
typedef __attribute__((ext_vector_type(8))) short s16x8;
typedef __attribute__((ext_vector_type(4))) short s16x4;
typedef __attribute__((ext_vector_type(4))) unsigned u32x4;

constexpr int NH  = 12;
constexpr int HD  = 64;
constexpr int DIM = 768;
constexpr int N   = 4096;
constexpr int QKV = 2304;
constexpr float LOG2E  = 1.4426950408889634f;
constexpr float SCALE2 = 0.125f * LOG2E;   // folded into kg at QKV epilogue

static __device__ __forceinline__ short f2bf(float f) {
  unsigned u = __builtin_bit_cast(unsigned, f);
  unsigned r = (u + 0x7FFFu + ((u >> 16) & 1u)) >> 16;  // RNE
  return (short)r;
}
static __device__ __forceinline__ float bf2f(short s) {
  unsigned u = ((unsigned)(unsigned short)s) << 16;
  return __builtin_bit_cast(float, u);
}
static __device__ __forceinline__ unsigned cvt_pk_bf16(float a, float b) {
  unsigned r;
  asm("v_cvt_pk_bf16_f32 %0, %1, %2" : "=v"(r) : "v"(a), "v"(b));
  return r;
}
static __device__ __forceinline__ float ex2(float x) {
  float r;
  asm("v_exp_f32 %0, %1" : "=v"(r) : "v"(x));
  return r;
}
static __device__ __forceinline__ void gload16(const void* g, void* l) {
  __builtin_amdgcn_global_load_lds(
      (const __attribute__((address_space(1))) void*)g,
      (__attribute__((address_space(3))) void*)l, 16, 0, 0);
}
static __device__ __forceinline__ void barrier_pre() {
  __builtin_amdgcn_s_barrier();
  __builtin_amdgcn_sched_barrier(0);
}
static __device__ __forceinline__ void barrier_post() {
  __builtin_amdgcn_sched_barrier(0);
  __builtin_amdgcn_s_barrier();
  __builtin_amdgcn_sched_barrier(0);
}

// ---------------------------------------------------------------------------
// K0: W_eff = w_qkv + lora_B @ lora_A  (bf16 out, [2304][768])
// ---------------------------------------------------------------------------
__global__ __launch_bounds__(256) void k_weff(const float* __restrict__ w_qkv,
                                              const float* __restrict__ lora_A,
                                              const float* __restrict__ lora_B,
                                              short* __restrict__ weff) {
  int e = blockIdx.x * 256 + threadIdx.x;
  if (e >= QKV * DIM) return;
  int r = e / DIM, c = e % DIM;
  float acc = w_qkv[e];
#pragma unroll
  for (int t = 0; t < 12; ++t) acc += lora_B[r * 12 + t] * lora_A[t * DIM + c];
  weff[e] = f2bf(acc);
}

// ---------------------------------------------------------------------------
// K0b: x fp32 -> bf16
// ---------------------------------------------------------------------------
__global__ __launch_bounds__(256) void k_x2bf(const float* __restrict__ x,
                                              short* __restrict__ xb) {
  int i = blockIdx.x * 256 + threadIdx.x;
  fvec4 v = *reinterpret_cast<const fvec4*>(x + (size_t)i * 4);
  s16x4 p;
  p[0] = f2bf(v[0]); p[1] = f2bf(v[1]); p[2] = f2bf(v[2]); p[3] = f2bf(v[3]);
  *reinterpret_cast<s16x4*>(xb + (size_t)i * 4) = p;
}

// ---------------------------------------------------------------------------
// K0c: w_proj -> split-bf16 B' [768][2304] = [Whi | Wlo | Whi]
// ---------------------------------------------------------------------------
__global__ __launch_bounds__(256) void k_wsplit(const float* __restrict__ w,
                                                short* __restrict__ ws) {
  int r = blockIdx.y;
  int kk = blockIdx.x * 256 + threadIdx.x;
  int blk = (kk >= 1536) ? 2 : (kk >= 768 ? 1 : 0);
  int c = kk - blk * 768;
  float wv = w[(size_t)r * 768 + c];
  short hi = f2bf(wv);
  ws[(size_t)r * 2304 + kk] = (blk == 1) ? f2bf(wv - bf2f(hi)) : hi;
}

// ---------------------------------------------------------------------------
// BMx128 MFMA GEMM, BK=64, double-buffered, counted vmcnt + raw barriers.
// MODE 0: qkv scatter (k scaled by SCALE2).  MODE 1: fp32 out + bias.
// ---------------------------------------------------------------------------
template <int KIT, int MODE, int BM>
__global__ __launch_bounds__(256, 2) void k_gemm(const short* __restrict__ A,
                                                 const short* __restrict__ B,
                                                 const float* __restrict__ bias,
                                                 short* __restrict__ qo,
                                                 short* __restrict__ ko,
                                                 short* __restrict__ vo,
                                                 float* __restrict__ outf) {
  constexpr int MFR = BM / 32;              // A m-frags per wave
  constexpr int BUFB = BM * 128 + 16384;    // bytes per buffer (A + B tiles)
  __shared__ __align__(16) char lds[2 * BUFB];
  const int tid = threadIdx.x;
  const int wave = tid >> 6, lane = tid & 63, lr = lane & 15, lg = lane >> 4;
  const int wr = wave >> 1, wc = wave & 1;
  const int i0 = blockIdx.x * BM, j0 = blockIdx.y * 128;
  const int LDA = KIT * 128;  // row bytes

  size_t offA[MFR], offB[4];
#pragma unroll
  for (int it = 0; it < MFR; ++it) {
    int c = it * 256 + tid;
    int row = c >> 3;
    offA[it] = (size_t)row * LDA + (((c & 7) << 4) ^ ((row & 7) << 4));
  }
#pragma unroll
  for (int it = 0; it < 4; ++it) {
    int c = it * 256 + tid;
    int row = c >> 3;
    offB[it] = (size_t)row * LDA + (((c & 7) << 4) ^ ((row & 7) << 4));
  }
  const char* Ab = (const char*)A + (size_t)i0 * LDA;
  const char* Bb = (const char*)B + (size_t)j0 * LDA;

  auto STAGE = [&](int kt, int b) {
    char* base = lds + b * BUFB;
    const size_t kadd = (size_t)kt * 128;
#pragma unroll
    for (int it = 0; it < MFR; ++it)
      gload16(Ab + kadd + offA[it], base + wave * 1024 + it * 4096);
#pragma unroll
    for (int it = 0; it < 4; ++it)
      gload16(Bb + kadd + offB[it], base + BM * 128 + wave * 1024 + it * 4096);
  };

  const int swz = (lr & 7) << 4;
  const int ab = (wr * (BM / 2) + lr) * 128 + ((lg * 16) ^ swz);
  const int bb = BM * 128 + (wc * 64 + lr) * 128 + ((lg * 16) ^ swz);

  f32x4 acc[MFR][4] = {};

  STAGE(0, 0);
  for (int kt = 0; kt < KIT; ++kt) {
    const int buf = kt & 1;
    if (kt + 1 < KIT) {
      STAGE(kt + 1, buf ^ 1);
      if constexpr (BM == 128)
        asm volatile("s_waitcnt vmcnt(8)" ::: "memory");
      else
        asm volatile("s_waitcnt vmcnt(6)" ::: "memory");
    } else {
      asm volatile("s_waitcnt vmcnt(0)" ::: "memory");
    }
    barrier_pre();
    const char* bufp = lds + buf * BUFB;
#pragma unroll
    for (int ks2 = 0; ks2 < 2; ++ks2) {
      s16x8 af[MFR], bf_[4];
#pragma unroll
      for (int m = 0; m < MFR; ++m)
        af[m] = *reinterpret_cast<const s16x8*>(bufp + ((ab + m * 2048) ^ (ks2 << 6)));
#pragma unroll
      for (int n = 0; n < 4; ++n)
        bf_[n] = *reinterpret_cast<const s16x8*>(bufp + ((bb + n * 2048) ^ (ks2 << 6)));
#pragma unroll
      for (int m = 0; m < MFR; ++m)
#pragma unroll
        for (int n = 0; n < 4; ++n)
          acc[m][n] = __builtin_amdgcn_mfma_f32_16x16x32_bf16(af[m], bf_[n], acc[m][n], 0, 0, 0);
    }
    barrier_post();
  }

  if constexpr (MODE == 0) {
    const int three = j0 / 768;
    const int head = ((j0 % 768) >> 6) + wc;
    const float osc = (three == 1) ? SCALE2 : 1.0f;  // fold SCALE*log2e into K
    short* dst = (three == 0) ? qo : ((three == 1) ? ko : vo);
#pragma unroll
    for (int n = 0; n < 4; ++n) {
      const int col = n * 16 + lr;
      const float bj = bias[j0 + wc * 64 + col];
#pragma unroll
      for (int m = 0; m < MFR; ++m)
#pragma unroll
        for (int r = 0; r < 4; ++r) {
          int i = i0 + wr * (BM / 2) + m * 16 + lg * 4 + r;
          dst[((size_t)head * N + i) * HD + col] = f2bf((acc[m][n][r] + bj) * osc);
        }
    }
  } else {
#pragma unroll
    for (int n = 0; n < 4; ++n) {
      const int j = j0 + wc * 64 + n * 16 + lr;
      const float bj = bias[j];
#pragma unroll
      for (int m = 0; m < MFR; ++m)
#pragma unroll
        for (int r = 0; r < 4; ++r) {
          int i = i0 + wr * (BM / 2) + m * 16 + lg * 4 + r;
          outf[(size_t)i * 768 + j] = acc[m][n][r] + bj;
        }
    }
  }
}

// ---------------------------------------------------------------------------
// K1b: vT[h][c][i] = v[h][i][c]
// ---------------------------------------------------------------------------
__global__ __launch_bounds__(256) void k_vT(const short* __restrict__ vg,
                                            short* __restrict__ vTg) {
  __shared__ short ts[64 * 72];
  const int tid = threadIdx.x;
  const int i0 = blockIdx.x * 64;
  const int h = blockIdx.y;
#pragma unroll
  for (int it = 0; it < 2; ++it) {
    int ch = tid + 256 * it;
    int row = ch >> 3, cc = (ch & 7) * 8;
    *reinterpret_cast<s16x8*>(&ts[row * 72 + cc]) =
        *reinterpret_cast<const s16x8*>(&vg[((size_t)h * N + i0 + row) * HD + cc]);
  }
  __syncthreads();
#pragma unroll
  for (int it = 0; it < 2; ++it) {
    int ch = tid + 256 * it;
    int c = ch >> 3, ii = (ch & 7) * 8;
    s16x8 o;
#pragma unroll
    for (int j = 0; j < 8; ++j) o[j] = ts[(ii + j) * 72 + c];
    *reinterpret_cast<s16x8*>(&vTg[((size_t)h * HD + c) * N + i0 + ii]) = o;
  }
}

// ---------------------------------------------------------------------------
// K2a: rel_h via MFMA, stored TRANSPOSED & pre-scaled by log2e:
// rhT[h][qh][kh][qw] = log2e * dot(q, tab[qh-kh+63])
// ---------------------------------------------------------------------------
__global__ __launch_bounds__(256) void k_relh(const short* __restrict__ qg,
                                              const float* __restrict__ tab,
                                              short* __restrict__ rhT) {
  __shared__ short Ts[64 * 72];
  const int tid = threadIdx.x;
  const int wave = tid >> 6, lane = tid & 63, lr = lane & 15, lg = lane >> 4;
  const int h = blockIdx.x >> 6, qh = blockIdx.x & 63;
#pragma unroll
  for (int it = 0; it < 4; ++it) {
    int e = tid + 256 * it;
    int row = e >> 4, c4 = (e & 15) * 4;  // row = kh
    fvec4 v = *reinterpret_cast<const fvec4*>(tab + (size_t)(qh + 63 - row) * 64 + c4);
    s16x4 p;
    p[0] = f2bf(v[0]); p[1] = f2bf(v[1]); p[2] = f2bf(v[2]); p[3] = f2bf(v[3]);
    *reinterpret_cast<s16x4*>(&Ts[row * 72 + c4]) = p;
  }
  __syncthreads();
  const size_t qrow = (size_t)h * N + qh * 64 + wave * 16 + lr;
  const s16x8 a0 = *reinterpret_cast<const s16x8*>(qg + qrow * 64 + lg * 8);
  const s16x8 a1 = *reinterpret_cast<const s16x8*>(qg + qrow * 64 + 32 + lg * 8);
  f32x4 acc[4] = {};
#pragma unroll
  for (int ks2 = 0; ks2 < 2; ++ks2)
#pragma unroll
    for (int n = 0; n < 4; ++n) {
      s16x8 b = *reinterpret_cast<const s16x8*>(&Ts[(n * 16 + lr) * 72 + ks2 * 32 + lg * 8]);
      acc[n] = __builtin_amdgcn_mfma_f32_16x16x32_bf16(ks2 ? a1 : a0, b, acc[n], 0, 0, 0);
    }
  const size_t ob = ((size_t)(h * 64 + qh)) * 4096;
#pragma unroll
  for (int n = 0; n < 4; ++n) {
    s16x4 o;
#pragma unroll
    for (int r = 0; r < 4; ++r) o[r] = f2bf(acc[n][r] * LOG2E);
    *reinterpret_cast<s16x4*>(&rhT[ob + (size_t)(n * 16 + lr) * 64 + wave * 16 + lg * 4]) = o;
  }
}

// ---------------------------------------------------------------------------
// K2b: rel_w via U-GEMM + scatter, pre-scaled by log2e.
// ---------------------------------------------------------------------------
__global__ __launch_bounds__(256) void k_relw(const short* __restrict__ qg,
                                              const float* __restrict__ tab,
                                              short* __restrict__ rwg) {
  __shared__ short Ts[128 * 72];
  const int tid = threadIdx.x;
  const int wave = tid >> 6, lane = tid & 63, lr = lane & 15, lg = lane >> 4;
  const int h = blockIdx.x >> 6, qh = blockIdx.x & 63;
#pragma unroll
  for (int it = 0; it < 8; ++it) {
    int e = tid + 256 * it;
    int row = e >> 4, c4 = (e & 15) * 4;  // row = d
    s16x4 p = {0, 0, 0, 0};
    if (row < 127) {
      fvec4 v = *reinterpret_cast<const fvec4*>(tab + (size_t)row * 64 + c4);
      p[0] = f2bf(v[0]); p[1] = f2bf(v[1]); p[2] = f2bf(v[2]); p[3] = f2bf(v[3]);
    }
    *reinterpret_cast<s16x4*>(&Ts[row * 72 + c4]) = p;
  }
  __syncthreads();
  const size_t qrow = (size_t)h * N + qh * 64 + wave * 16 + lr;
  const s16x8 a0 = *reinterpret_cast<const s16x8*>(qg + qrow * 64 + lg * 8);
  const s16x8 a1 = *reinterpret_cast<const s16x8*>(qg + qrow * 64 + 32 + lg * 8);
  f32x4 acc[8] = {};
#pragma unroll
  for (int ks2 = 0; ks2 < 2; ++ks2)
#pragma unroll
    for (int n = 0; n < 8; ++n) {
      s16x8 b = *reinterpret_cast<const s16x8*>(&Ts[(n * 16 + lr) * 72 + ks2 * 32 + lg * 8]);
      acc[n] = __builtin_amdgcn_mfma_f32_16x16x32_bf16(ks2 ? a1 : a0, b, acc[n], 0, 0, 0);
    }
  const size_t ob = ((size_t)h * N + qh * 64) * 64;
#pragma unroll
  for (int n = 0; n < 8; ++n) {
    int d = n * 16 + lr;
#pragma unroll
    for (int r = 0; r < 4; ++r) {
      int qw = wave * 16 + lg * 4 + r;
      int kw = qw + 63 - d;
      if ((unsigned)kw < 64u) rwg[ob + (size_t)qw * 64 + kw] = f2bf(acc[n][r] * LOG2E);
    }
  }
}

// ---------------------------------------------------------------------------
// K3: flash attention (r4's proven syncthreads loop + folds).
// Block = (h, qt: 64 q rows), 4 waves = (kt2, kh2) over a 128-key double
// tile; waves 0/1 stage K rows, waves 2/3 stage V; __syncthreads() per
// iteration makes the cross-wave staging safe (implied vmcnt(0) drain).
// Softmax: p = ex2(sa + rh + rw)  (scales folded upstream).
// LDS: dbuf 2 x { K[128][128B] @0, V[2][64][128B] @16K } = 64KB.
// ---------------------------------------------------------------------------
#define QG_BLOCK(QB0, QB1, QB2, QB3, RW, RH2, ACC0, ACC1, LA, LB)              \
  do {                                                                         \
    f32x16 sa = {};                                                            \
    __builtin_amdgcn_s_setprio(1);                                             \
    sa = __builtin_amdgcn_mfma_f32_32x32x16_bf16(kf0, QB0, sa, 0, 0, 0);       \
    sa = __builtin_amdgcn_mfma_f32_32x32x16_bf16(kf1, QB1, sa, 0, 0, 0);       \
    sa = __builtin_amdgcn_mfma_f32_32x32x16_bf16(kf2, QB2, sa, 0, 0, 0);       \
    sa = __builtin_amdgcn_mfma_f32_32x32x16_bf16(kf3, QB3, sa, 0, 0, 0);       \
    __builtin_amdgcn_s_setprio(0);                                             \
    float p[16];                                                               \
    _Pragma("unroll")                                                          \
    for (int reg = 0; reg < 16; ++reg)                                         \
      p[reg] = ex2(sa[reg] + RH2 + RW[reg]);                                   \
    float t0 = (p[0] + p[1]) + (p[2] + p[3]);                                  \
    float t1 = (p[4] + p[5]) + (p[6] + p[7]);                                  \
    float t2 = (p[8] + p[9]) + (p[10] + p[11]);                                \
    float t3 = (p[12] + p[13]) + (p[14] + p[15]);                              \
    LA += t0 + t1;                                                             \
    LB += t2 + t3;                                                             \
    unsigned w00 = cvt_pk_bf16(p[0], p[1]),   w01 = cvt_pk_bf16(p[2], p[3]);   \
    unsigned w10 = cvt_pk_bf16(p[4], p[5]),   w11 = cvt_pk_bf16(p[6], p[7]);   \
    unsigned w20 = cvt_pk_bf16(p[8], p[9]),   w21 = cvt_pk_bf16(p[10], p[11]); \
    unsigned w30 = cvt_pk_bf16(p[12], p[13]), w31 = cvt_pk_bf16(p[14], p[15]); \
    asm("v_permlane32_swap_b32 %0, %1" : "+v"(w00), "+v"(w10));                \
    asm("v_permlane32_swap_b32 %0, %1" : "+v"(w01), "+v"(w11));                \
    asm("v_permlane32_swap_b32 %0, %1" : "+v"(w20), "+v"(w30));                \
    asm("v_permlane32_swap_b32 %0, %1" : "+v"(w21), "+v"(w31));                \
    u32x4 u0 = {w00, w01, w10, w11};                                           \
    u32x4 u1 = {w20, w21, w30, w31};                                           \
    s16x8 pa0 = __builtin_bit_cast(s16x8, u0);                                 \
    s16x8 pa1 = __builtin_bit_cast(s16x8, u1);                                 \
    __builtin_amdgcn_s_setprio(1);                                             \
    ACC0 = __builtin_amdgcn_mfma_f32_32x32x16_bf16(pa0, vf0, ACC0, 0, 0, 0);   \
    ACC0 = __builtin_amdgcn_mfma_f32_32x32x16_bf16(pa1, vf2, ACC0, 0, 0, 0);   \
    ACC1 = __builtin_amdgcn_mfma_f32_32x32x16_bf16(pa0, vf1, ACC1, 0, 0, 0);   \
    ACC1 = __builtin_amdgcn_mfma_f32_32x32x16_bf16(pa1, vf3, ACC1, 0, 0, 0);   \
    __builtin_amdgcn_s_setprio(0);                                             \
  } while (0)

__global__ __launch_bounds__(256, 2) void k_flash(const short* __restrict__ qg,
                                                  const short* __restrict__ kg,
                                                  const short* __restrict__ vTg,
                                                  const short* __restrict__ rhTg,
                                                  const short* __restrict__ rwg,
                                                  short* __restrict__ aprime) {
  __shared__ __align__(16) char lds[65536];
  const int tid = threadIdx.x;
  const int wave = tid >> 6, lane = tid & 63;
  const int ql = lane & 31, hi = lane >> 5;
  const int kt2 = wave & 1, kh2 = wave >> 1;
  const int bid = blockIdx.x;
  const int id = (bid & 7) * 96 + (bid >> 3);  // bijective XCD swizzle (768%8==0)
  const int h = id >> 6, qt = id & 63;
  const int i0 = qt * 64;

  // Q fragments in registers
  const short* q0p = qg + ((size_t)h * N + i0 + ql) * 64 + hi * 8;
  const short* q1p = q0p + 32 * 64;
  const s16x8 qb00 = *reinterpret_cast<const s16x8*>(q0p);
  const s16x8 qb01 = *reinterpret_cast<const s16x8*>(q0p + 16);
  const s16x8 qb02 = *reinterpret_cast<const s16x8*>(q0p + 32);
  const s16x8 qb03 = *reinterpret_cast<const s16x8*>(q0p + 48);
  const s16x8 qb10 = *reinterpret_cast<const s16x8*>(q1p);
  const s16x8 qb11 = *reinterpret_cast<const s16x8*>(q1p + 16);
  const s16x8 qb12 = *reinterpret_cast<const s16x8*>(q1p + 32);
  const s16x8 qb13 = *reinterpret_cast<const s16x8*>(q1p + 48);

  // rel_w preload (log2e pre-scaled by producer)
  f32x16 rw0, rw1;
  {
    const short* rwp0 = rwg + ((size_t)h * N + i0 + ql) * 64 + kh2 * 32 + hi * 4;
    const short* rwp1 = rwp0 + 32 * 64;
#pragma unroll
    for (int reg = 0; reg < 16; ++reg) {
      int o = (reg & 3) + 8 * (reg >> 2);
      rw0[reg] = bf2f(rwp0[o]);
      rw1[reg] = bf2f(rwp1[o]);
    }
  }
  const short* rhp = rhTg + ((size_t)(h * 64 + qt)) * 4096;

  // staging offsets (inverse-swizzled).  waves 0/1: K rows; waves 2/3: V.
  int soff[8];
  const char* sbase;
  if (wave < 2) {
    sbase = (const char*)kg + (size_t)h * N * 128 + wave * 64 * 128;
#pragma unroll
    for (int it = 0; it < 8; ++it) {
      int c = it * 64 + lane, row = c >> 3;
      soff[it] = row * 128 + (((c & 7) << 4) ^ ((row & 7) << 4));
    }
  } else {
    sbase = (const char*)vTg + (size_t)h * 64 * 8192 + (wave - 2) * 128;
#pragma unroll
    for (int it = 0; it < 8; ++it) {
      int c = it * 64 + lane, r = c >> 3;
      soff[it] = r * 8192 + (((c & 7) << 4) ^ ((r & 7) << 4));
    }
  }
  const int sstep = (wave < 2) ? 16384 : 256;
  char* lreg = lds + wave * 8192;

  auto STAGE = [&](int i, int buf) {
    const char* sp = sbase + (size_t)i * sstep;
    char* lp = lreg + buf * 32768;
#pragma unroll
    for (int it = 0; it < 8; ++it) gload16(sp + soff[it], lp + it * 1024);
  };

  // fragment read offsets (within a buffer)
  const int swzq = (ql & 7) << 4;
  const int krow = (kt2 * 64 + kh2 * 32 + ql) * 128;
  const int kco0 = krow + ((0 * 32 + hi * 16) ^ swzq);
  const int kco1 = krow + ((1 * 32 + hi * 16) ^ swzq);
  const int kco2 = krow + ((2 * 32 + hi * 16) ^ swzq);
  const int kco3 = krow + ((3 * 32 + hi * 16) ^ swzq);
  const int vrow0 = 16384 + kt2 * 8192 + ql * 128;
  const int vrow1 = vrow0 + 32 * 128;
  const int vch0 = (kh2 * 64 + 0 * 32 + hi * 16) ^ swzq;
  const int vch1 = (kh2 * 64 + 1 * 32 + hi * 16) ^ swzq;
  const int vco0 = vrow0 + vch0;
  const int vco1 = vrow1 + vch0;
  const int vco2 = vrow0 + vch1;
  const int vco3 = vrow1 + vch1;

  f32x16 acc00 = {}, acc01 = {}, acc10 = {}, acc11 = {};
  float la0 = 0.f, lb0 = 0.f, la1 = 0.f, lb1 = 0.f;

  // rel_h prefetch (kh = i*2 + kt2), producers pre-scaled by log2e
  unsigned short rhc0 = (unsigned short)rhp[(size_t)kt2 * 64 + ql];
  unsigned short rhc1 = (unsigned short)rhp[(size_t)kt2 * 64 + 32 + ql];

  STAGE(0, 0);
  __syncthreads();   // drains vmcnt(0): tile 0 landed for ALL waves

  for (int i = 0; i < 32; ++i) {
    const int buf = i & 1;
    if (i + 1 < 32) STAGE(i + 1, buf ^ 1);
    const int nx = (i + 1 < 32) ? i + 1 : 31;
    unsigned short rhn0 = (unsigned short)rhp[(size_t)(nx * 2 + kt2) * 64 + ql];
    unsigned short rhn1 = (unsigned short)rhp[(size_t)(nx * 2 + kt2) * 64 + 32 + ql];

    const char* bufp = lds + buf * 32768;
    s16x8 kf0 = *reinterpret_cast<const s16x8*>(bufp + kco0);
    s16x8 kf1 = *reinterpret_cast<const s16x8*>(bufp + kco1);
    s16x8 kf2 = *reinterpret_cast<const s16x8*>(bufp + kco2);
    s16x8 kf3 = *reinterpret_cast<const s16x8*>(bufp + kco3);
    s16x8 vf0 = *reinterpret_cast<const s16x8*>(bufp + vco0);
    s16x8 vf1 = *reinterpret_cast<const s16x8*>(bufp + vco1);
    s16x8 vf2 = *reinterpret_cast<const s16x8*>(bufp + vco2);
    s16x8 vf3 = *reinterpret_cast<const s16x8*>(bufp + vco3);

    const float rh20 = bf2f((short)rhc0);
    const float rh21 = bf2f((short)rhc1);

    QG_BLOCK(qb00, qb01, qb02, qb03, rw0, rh20, acc00, acc01, la0, lb0);
    QG_BLOCK(qb10, qb11, qb12, qb13, rw1, rh21, acc10, acc11, la1, lb1);

    rhc0 = rhn0; rhc1 = rhn1;
    __syncthreads();   // safe: drains next-tile staging + orders buffer reuse
  }

  // ---- epilogue: cross-wave reduction of l and O (r4/r6-proven) ----
  float l0 = la0 + lb0, l1 = la1 + lb1;
  l0 += __shfl_xor(l0, 32);
  l1 += __shfl_xor(l1, 32);
  float* LS = (float*)lds;               // [4 waves][64 q]
  if (lane < 32) {
    LS[wave * 64 + ql] = l0;
    LS[wave * 64 + 32 + ql] = l1;
  }
  __syncthreads();
  const int eq = wave * 16 + (lane >> 2);     // this thread's q row (epilogue)
  const int cb = (lane & 3) * 16;             // this thread's 16-col chunk
  float inv = 1.0f / (LS[eq] + LS[64 + eq] + LS[128 + eq] + LS[192 + eq]);
  __syncthreads();
  float* OF = (float*)lds;               // [4 waves][64 q][64 c], c XOR-swizzled
#pragma unroll
  for (int qg2 = 0; qg2 < 2; ++qg2)
#pragma unroll
    for (int ct = 0; ct < 2; ++ct) {
      const f32x16& a = qg2 ? (ct ? acc11 : acc10) : (ct ? acc01 : acc00);
#pragma unroll
      for (int reg = 0; reg < 16; ++reg) {
        int q = qg2 * 32 + (reg & 3) + 8 * (reg >> 2) + 4 * hi;
        int c = ct * 32 + ql;
        OF[wave * 4096 + q * 64 + (c ^ ((q & 7) << 2))] = a[reg];
      }
    }
  __syncthreads();
  f32x4 osum[4] = {};
#pragma unroll
  for (int w = 0; w < 4; ++w)
#pragma unroll
    for (int j = 0; j < 4; ++j)
      osum[j] += *reinterpret_cast<const f32x4*>(
          &OF[w * 4096 + eq * 64 + ((cb + j * 4) ^ ((eq & 7) << 2))]);

  s16x8 hi8[2], lo8[2];
#pragma unroll
  for (int j = 0; j < 4; ++j)
#pragma unroll
    for (int e = 0; e < 4; ++e) {
      float o = osum[j][e] * inv;
      short oh = f2bf(o);
      float lo = o - bf2f(oh);
      int idx = j * 4 + e;
      hi8[idx >> 3][idx & 7] = oh;
      lo8[idx >> 3][idx & 7] = f2bf(lo);
    }
  size_t obase = (size_t)(i0 + eq) * 2304 + h * 64 + cb;
  *reinterpret_cast<s16x8*>(&aprime[obase]) = hi8[0];
  *reinterpret_cast<s16x8*>(&aprime[obase + 8]) = hi8[1];
  *reinterpret_cast<s16x8*>(&aprime[obase + 768]) = hi8[0];
  *reinterpret_cast<s16x8*>(&aprime[obase + 776]) = hi8[1];
  *reinterpret_cast<s16x8*>(&aprime[obase + 1536]) = lo8[0];
  *reinterpret_cast<s16x8*>(&aprime[obase + 1544]) = lo8[1];
}

// ---------------------------------------------------------------------------
extern "C" void kernel_launch(void* const* d_in, const int* in_sizes, int n_in,
                              void* d_out, int out_size, void* d_ws, size_t ws_size,
                              hipStream_t stream) {
  const float* x      = (const float*)d_in[0];
  const float* w_qkv  = (const float*)d_in[1];
  const float* b_qkv  = (const float*)d_in[2];
  const float* lora_A = (const float*)d_in[3];
  const float* lora_B = (const float*)d_in[4];
  const float* w_proj = (const float*)d_in[5];
  const float* b_proj = (const float*)d_in[6];
  const float* rel_h  = (const float*)d_in[7];
  const float* rel_w  = (const float*)d_in[8];
  float* out = (float*)d_out;

  char* ws = (char*)d_ws;
  short* weff   = (short*)(ws + 0);           // dead before flash
  short* xb     = (short*)(ws + 3538944);     // dead before flash
  short* vg     = (short*)(ws + 9830400);     // dead before flash
  short* aprime = (short*)(ws + 0);           // overlays the above
  short* qg     = (short*)(ws + 18874368);
  short* kg     = (short*)(ws + 25165824);
  short* vTg    = (short*)(ws + 31457280);
  short* rhT    = (short*)(ws + 37748736);
  short* rwg    = (short*)(ws + 44040192);
  short* wsp    = (short*)(ws + 50331648);    // -> total 53,870,592
  (void)ws_size; (void)in_sizes; (void)n_in; (void)out_size;

  k_weff<<<dim3((QKV * DIM + 255) / 256), dim3(256), 0, stream>>>(w_qkv, lora_A, lora_B, weff);
  k_x2bf<<<dim3(3072), dim3(256), 0, stream>>>(x, xb);
  k_wsplit<<<dim3(9, 768), dim3(256), 0, stream>>>(w_proj, wsp);
  k_gemm<12, 0, 128><<<dim3(32, 18), dim3(256), 0, stream>>>(xb, weff, b_qkv, qg, kg, vg, nullptr);
  k_vT<<<dim3(64, NH), dim3(256), 0, stream>>>(vg, vTg);
  k_relh<<<dim3(NH * 64), dim3(256), 0, stream>>>(qg, rel_h, rhT);
  k_relw<<<dim3(NH * 64), dim3(256), 0, stream>>>(qg, rel_w, rwg);
  k_flash<<<dim3(NH * 64), dim3(256), 0, stream>>>(qg, kg, vTg, rhT, rwg, aprime);
  k_gemm<36, 1, 64><<<dim3(64, 6), dim3(256), 0, stream>>>(aprime, wsp, b_proj, nullptr, nullptr, nullptr, out);
}